// Round 11
// baseline (1141.112 us; speedup 1.0000x reference)
//
#include <hip/hip_runtime.h>
#include <math.h>

typedef __attribute__((ext_vector_type(8))) short short8;
typedef __attribute__((ext_vector_type(4))) float f32x4;

__device__ __forceinline__ unsigned short f2bf(float f) {
  unsigned u = __builtin_bit_cast(unsigned, f);
  u += 0x7fff + ((u >> 16) & 1);
  return (unsigned short)(u >> 16);
}
__device__ __forceinline__ float bf2f(unsigned short h) {
  unsigned u = ((unsigned)h) << 16;
  return __builtin_bit_cast(float, u);
}
__device__ __forceinline__ float gelu_f(float x) {
  const float c0 = 0.7978845608028654f;
  return 0.5f * x * (1.0f + tanhf(c0 * (x + 0.044715f * x * x * x)));
}
// async global->LDS, 16B per lane; LDS dest = wave-uniform base + lane*16
__device__ __forceinline__ void gload16(const unsigned short* g, unsigned short* l) {
  __builtin_amdgcn_global_load_lds(
      (const __attribute__((address_space(1))) unsigned int*)g,
      (__attribute__((address_space(3))) unsigned int*)l, 16, 0, 0);
}
// interleave map for kv rows: k elem e -> (e>>2)*8 + (e&3); v elem e -> (e>>2)*8+4+(e&3)
__device__ __forceinline__ int ileave512(int cc) {
  const int base = (cc & 256) ? 4 : 0;
  const int c2 = cc & 255;
  return (c2 >> 2) * 8 + base + (c2 & 3);
}

// ===== mega QKV GEMM: per z-context computes everything derived from one x =====
// N=2560 col split: [0,768) qT self; [768,1280) kvS (interleaved);
// [1280,2048) qT cross; [2048,2560) kvX (interleaved).
__global__ __launch_bounds__(256)
void gemm_qkv_k(const unsigned short* __restrict__ A0, const unsigned short* __restrict__ A1,
                const unsigned short* __restrict__ BT0, const unsigned short* __restrict__ BT1,
                unsigned short* __restrict__ qT0, unsigned short* __restrict__ qT1,
                unsigned short* __restrict__ kvS0, unsigned short* __restrict__ kvS1,
                unsigned short* __restrict__ kvX0, unsigned short* __restrict__ kvX1,
                int M)
{
  const int z = blockIdx.z;
  const unsigned short* A  = z ? A1  : A0;
  const unsigned short* BT = z ? BT1 : BT0;
  unsigned short* qT  = z ? qT1  : qT0;
  unsigned short* kvS = z ? kvS1 : kvS0;
  unsigned short* kvX = z ? kvX1 : kvX0;
  const int K = 256, lda = 256;

  __shared__ __align__(16) unsigned short As[128 * 32];
  __shared__ __align__(16) unsigned short Bs[128 * 32];
  const int tid = threadIdx.x;
  const int bm = blockIdx.x * 128, bn = blockIdx.y * 128;
  const int lane = tid & 63, w = tid >> 6;
  const int wr = w >> 1, wc = w & 1;
  const int l15 = lane & 15, kg = lane >> 4;
  const int srow0 = w * 16 + (lane >> 2);
  const int srow1 = 64 + srow0;
  const int sslot = lane & 3;
  const int koff0 = (((sslot - (srow0 >> 1)) & 3)) * 8;
  const int koff1 = (((sslot - (srow1 >> 1)) & 3)) * 8;
  const unsigned short* gA0 = A + (size_t)(bm + srow0) * lda + koff0;
  const unsigned short* gA1 = A + (size_t)(bm + srow1) * lda + koff1;
  const unsigned short* gB0 = BT + (size_t)(bn + srow0) * K + koff0;
  const unsigned short* gB1 = BT + (size_t)(bn + srow1) * K + koff1;
  unsigned short* lA0 = As + w * 512;
  unsigned short* lA1 = As + 2048 + w * 512;
  unsigned short* lB0 = Bs + w * 512;
  unsigned short* lB1 = Bs + 2048 + w * 512;

  int roffA[4], roffB[4];
#pragma unroll
  for (int m = 0; m < 4; ++m) {
    int row = wr * 64 + m * 16 + l15;
    roffA[m] = row * 32 + ((kg + (row >> 1)) & 3) * 8;
  }
#pragma unroll
  for (int n = 0; n < 4; ++n) {
    int col = wc * 64 + n * 16 + l15;
    roffB[n] = col * 32 + ((kg + (col >> 1)) & 3) * 8;
  }

  f32x4 acc[4][4] = {};
  for (int k0 = 0; k0 < K; k0 += 32) {
    gload16(gA0 + k0, lA0);
    gload16(gA1 + k0, lA1);
    gload16(gB0 + k0, lB0);
    gload16(gB1 + k0, lB1);
    __syncthreads();
    short8 af[4], bfr[4];
#pragma unroll
    for (int m = 0; m < 4; ++m) af[m] = *(const short8*)(As + roffA[m]);
#pragma unroll
    for (int n = 0; n < 4; ++n) bfr[n] = *(const short8*)(Bs + roffB[n]);
#pragma unroll
    for (int m = 0; m < 4; ++m)
#pragma unroll
      for (int n = 0; n < 4; ++n)
        acc[m][n] = __builtin_amdgcn_mfma_f32_16x16x32_bf16(af[m], bfr[n], acc[m][n], 0, 0, 0);
    __syncthreads();
  }
#pragma unroll
  for (int m = 0; m < 4; ++m) {
#pragma unroll
    for (int n = 0; n < 4; ++n) {
      int col = bn + wc * 64 + n * 16 + l15;
      f32x4 v = acc[m][n];
#pragma unroll
      for (int r2 = 0; r2 < 4; ++r2) {
        int row = bm + wr * 64 + m * 16 + kg * 4 + r2;
        unsigned short bv = f2bf(v[r2]);
        if (col < 768) {
          qT[(size_t)row * 1536 + col] = bv;
        } else if (col < 1280) {
          kvS[(size_t)row * 512 + ileave512(col - 768)] = bv;
        } else if (col < 2048) {
          qT[(size_t)row * 1536 + 768 + (col - 1280)] = bv;
        } else {
          kvX[(size_t)row * 512 + ileave512(col - 2048)] = bv;
        }
      }
    }
  }
}

// ===== generic 2-context bf16 MFMA GEMM (blockIdx.z = L/R) =====
// col split: [0,Sf)->f32 Cf, [Sf,S2)->bf16 Cb1, [S2,N)->bf16 Cb2 (plain layouts).
template<bool BIAS, bool GELU>
__global__ __launch_bounds__(256)
void gemm_mfma2_k(const unsigned short* __restrict__ A0, const unsigned short* __restrict__ A1,
                  int lda,
                  const unsigned short* __restrict__ BT0, const unsigned short* __restrict__ BT1,
                  const float* __restrict__ bias0, const float* __restrict__ bias1,
                  float* __restrict__ Cf0, float* __restrict__ Cf1, int Sf, int ldf,
                  unsigned short* __restrict__ Cb10, unsigned short* __restrict__ Cb11,
                  int S2, int ldb1,
                  unsigned short* __restrict__ Cb20, unsigned short* __restrict__ Cb21, int ldb2,
                  int M, int N, int K)
{
  const int z = blockIdx.z;
  const unsigned short* A  = z ? A1  : A0;
  const unsigned short* BT = z ? BT1 : BT0;
  const float* bias        = z ? bias1 : bias0;
  float* Cf                = z ? Cf1 : Cf0;
  unsigned short* Cb1      = z ? Cb11 : Cb10;
  unsigned short* Cb2      = z ? Cb21 : Cb20;

  __shared__ __align__(16) unsigned short As[128 * 32];
  __shared__ __align__(16) unsigned short Bs[128 * 32];
  const int tid = threadIdx.x;
  const int bm = blockIdx.x * 128, bn = blockIdx.y * 128;
  const int lane = tid & 63, w = tid >> 6;
  const int wr = w >> 1, wc = w & 1;
  const int l15 = lane & 15, kg = lane >> 4;
  const int srow0 = w * 16 + (lane >> 2);
  const int srow1 = 64 + srow0;
  const int sslot = lane & 3;
  const int koff0 = (((sslot - (srow0 >> 1)) & 3)) * 8;
  const int koff1 = (((sslot - (srow1 >> 1)) & 3)) * 8;
  const unsigned short* gA0 = A + (size_t)(bm + srow0) * lda + koff0;
  const unsigned short* gA1 = A + (size_t)(bm + srow1) * lda + koff1;
  const unsigned short* gB0 = BT + (size_t)(bn + srow0) * K + koff0;
  const unsigned short* gB1 = BT + (size_t)(bn + srow1) * K + koff1;
  unsigned short* lA0 = As + w * 512;
  unsigned short* lA1 = As + 2048 + w * 512;
  unsigned short* lB0 = Bs + w * 512;
  unsigned short* lB1 = Bs + 2048 + w * 512;

  int roffA[4], roffB[4];
#pragma unroll
  for (int m = 0; m < 4; ++m) {
    int row = wr * 64 + m * 16 + l15;
    roffA[m] = row * 32 + ((kg + (row >> 1)) & 3) * 8;
  }
#pragma unroll
  for (int n = 0; n < 4; ++n) {
    int col = wc * 64 + n * 16 + l15;
    roffB[n] = col * 32 + ((kg + (col >> 1)) & 3) * 8;
  }

  f32x4 acc[4][4] = {};
  for (int k0 = 0; k0 < K; k0 += 32) {
    gload16(gA0 + k0, lA0);
    gload16(gA1 + k0, lA1);
    gload16(gB0 + k0, lB0);
    gload16(gB1 + k0, lB1);
    __syncthreads();
    short8 af[4], bfr[4];
#pragma unroll
    for (int m = 0; m < 4; ++m) af[m] = *(const short8*)(As + roffA[m]);
#pragma unroll
    for (int n = 0; n < 4; ++n) bfr[n] = *(const short8*)(Bs + roffB[n]);
#pragma unroll
    for (int m = 0; m < 4; ++m)
#pragma unroll
      for (int n = 0; n < 4; ++n)
        acc[m][n] = __builtin_amdgcn_mfma_f32_16x16x32_bf16(af[m], bfr[n], acc[m][n], 0, 0, 0);
    __syncthreads();
  }
#pragma unroll
  for (int m = 0; m < 4; ++m) {
#pragma unroll
    for (int n = 0; n < 4; ++n) {
      int col = bn + wc * 64 + n * 16 + l15;
      float bv = BIAS ? bias[col] : 0.f;
      f32x4 v = acc[m][n];
#pragma unroll
      for (int r2 = 0; r2 < 4; ++r2) {
        int row = bm + wr * 64 + m * 16 + kg * 4 + r2;
        float val = v[r2] + bv;
        if (GELU) val = gelu_f(val);
        if (col < Sf) {
          Cf[(size_t)row * ldf + col] = val;
        } else if (col < S2) {
          Cb1[(size_t)row * ldb1 + (col - Sf)] = f2bf(val);
        } else {
          Cb2[(size_t)row * ldb2 + (col - S2)] = f2bf(val);
        }
      }
    }
  }
}

// ===== f32 GEMM, 2-context (tiny N=7 head2) =====
template<bool BIAS>
__global__ __launch_bounds__(256)
void gemm_k2(const float* __restrict__ A0, const float* __restrict__ A1,
             const float* __restrict__ B, const float* __restrict__ bias,
             float* __restrict__ C0, float* __restrict__ C1,
             int M, int N, int K)
{
  const float* A = blockIdx.z ? A1 : A0;
  float* C = blockIdx.z ? C1 : C0;
  __shared__ float As[16][132];
  __shared__ float Bs[16][132];
  const int tid = threadIdx.x;
  const int tx = tid & 15, ty = tid >> 4;
  const int bm = blockIdx.x * 128;
  float acc[8][8];
#pragma unroll
  for (int i = 0; i < 8; ++i)
#pragma unroll
    for (int j = 0; j < 8; ++j) acc[i][j] = 0.f;
  const int ar = tid >> 1;
  const int ac = (tid & 1) * 8;
  const int br = tid >> 4;
  const int bc = (tid & 15) * 8;
  for (int k0 = 0; k0 < K; k0 += 16) {
    {
      float av[8] = {0,0,0,0,0,0,0,0};
      if (bm + ar < M) {
        const float* app = A + (size_t)(bm + ar) * K + (k0 + ac);
        float4 a0 = *(const float4*)app;
        float4 a1 = *(const float4*)(app + 4);
        av[0]=a0.x; av[1]=a0.y; av[2]=a0.z; av[3]=a0.w;
        av[4]=a1.x; av[5]=a1.y; av[6]=a1.z; av[7]=a1.w;
      }
#pragma unroll
      for (int i = 0; i < 8; ++i) As[ac + i][ar] = av[i];
    }
    {
      float bv[8] = {0,0,0,0,0,0,0,0};
      const float* bpp = B + (size_t)(k0 + br) * N + bc;
#pragma unroll
      for (int i = 0; i < 8; ++i) { if (bc + i < N) bv[i] = bpp[i]; }
#pragma unroll
      for (int i = 0; i < 8; ++i) Bs[br][bc + i] = bv[i];
    }
    __syncthreads();
#pragma unroll
    for (int kk = 0; kk < 16; ++kk) {
      float a[8], b[8];
      float4 t0 = *(const float4*)&As[kk][ty * 8];
      float4 t1 = *(const float4*)&As[kk][ty * 8 + 4];
      float4 u0 = *(const float4*)&Bs[kk][tx * 8];
      float4 u1 = *(const float4*)&Bs[kk][tx * 8 + 4];
      a[0]=t0.x;a[1]=t0.y;a[2]=t0.z;a[3]=t0.w;a[4]=t1.x;a[5]=t1.y;a[6]=t1.z;a[7]=t1.w;
      b[0]=u0.x;b[1]=u0.y;b[2]=u0.z;b[3]=u0.w;b[4]=u1.x;b[5]=u1.y;b[6]=u1.z;b[7]=u1.w;
#pragma unroll
      for (int i = 0; i < 8; ++i)
#pragma unroll
        for (int j = 0; j < 8; ++j)
          acc[i][j] = fmaf(a[i], b[j], acc[i][j]);
    }
    __syncthreads();
  }
#pragma unroll
  for (int i = 0; i < 8; ++i) {
    int row = bm + ty * 8 + i;
    if (row >= M) continue;
    int colg = tx * 8;
    float* cp = C + (size_t)row * N + colg;
#pragma unroll
    for (int j = 0; j < 8; ++j) {
      int cc = colg + j;
      if (cc < N) {
        float val = acc[i][j];
        if (BIAS) val += bias[cc];
        cp[j] = val;
      }
    }
  }
}

// ===== generic transpose+convert (FFN / head weights) =====
__global__ void tc_k(const float* __restrict__ in, unsigned short* __restrict__ out,
                     int K, int N, int inStride, int outStride, int rowOff, int totK, int kOff)
{
  const int mat = blockIdx.y;
  const int idx = blockIdx.x * 256 + threadIdx.x;
  if (idx >= N * K) return;
  const int n = idx / K, k = idx - n * K;
  out[(size_t)mat * outStride + (size_t)(rowOff + n) * totK + kOff + k] =
      f2bf(in[(size_t)mat * inStride + (size_t)k * N + n]);
}

// ===== mega-QKV weight pack: 6 parts x 4 slots (l,side) =====
__global__ void tc_all_k(const float* __restrict__ Wq, const float* __restrict__ Wk,
                         const float* __restrict__ Wv, unsigned short* __restrict__ BTall)
{
  const int part = blockIdx.z;
  const int slot = blockIdx.y;
  const int l = slot >> 1, zz = slot & 1;
  const int self = l * 4 + zz;
  const int crossq = l * 4 + (zz ? 2 : 3);
  const int crosskv = l * 4 + (zz ? 3 : 2);
  const float* in; int mat, rowOff;
  switch (part) {
    case 0: in = Wq; mat = self;    rowOff = 0;    break;
    case 1: in = Wk; mat = self;    rowOff = 768;  break;
    case 2: in = Wv; mat = self;    rowOff = 1024; break;
    case 3: in = Wq; mat = crossq;  rowOff = 1280; break;
    case 4: in = Wk; mat = crosskv; rowOff = 2048; break;
    default:in = Wv; mat = crosskv; rowOff = 2304; break;
  }
  const int idx = blockIdx.x * 256 + threadIdx.x;
  const int n = idx >> 8, k = idx & 255;
  BTall[(size_t)slot * 655360 + (size_t)(rowOff + n) * 256 + k] =
      f2bf(in[(size_t)mat * 65536 + (size_t)k * 256 + n]);
}

// ===== fused T-weights inside BTall (self rows 256..767; cross rows 1536..2047) =====
__global__ __launch_bounds__(256)
void wqe2_k(unsigned short* __restrict__ BTall, const float* __restrict__ We)
{
  const int which = blockIdx.z;        // 0 self, 1 cross
  const int slot = blockIdx.y;
  const int l = slot >> 1, zz = slot & 1;
  const int mat = which ? (l * 4 + (zz ? 2 : 3)) : (l * 4 + zz);
  const int baseQ = which ? 1280 : 0;
  const int baseT = which ? 1536 : 256;
  const int oc = blockIdx.x;           // 0..511 = head*64 + c
  const int g = oc >> 6, cc = oc & 63;
  const int kin = threadIdx.x;         // 0..255
  const float* wrow = We + (size_t)mat * 16384 + (size_t)cc * 256 + g * 32;
  const unsigned short* bq = BTall + (size_t)slot * 655360 + (size_t)(baseQ + g * 32) * 256 + kin;
  float acc = 0.f;
#pragma unroll 8
  for (int d = 0; d < 32; ++d)
    acc += bf2f(bq[(size_t)d * 256]) * wrow[d];
  BTall[(size_t)slot * 655360 + (size_t)(baseT + oc) * 256 + kin] = f2bf(acc);
}

// ===== fused Wo pack: BTwoF[sl][n][base + k] = Wo[mat][k][n] =====
__global__ void wo_tc_k(const float* __restrict__ Wo, unsigned short* __restrict__ BTwoF)
{
  const int mat = blockIdx.y;          // 0..7 = l*4+i
  const int idx = blockIdx.x * 256 + threadIdx.x;
  const int n = idx >> 8, k = idx & 255;
  const int l = mat >> 2, i = mat & 3;
  const int side = (i == 1 || i == 2) ? 1 : 0;
  const int base = (i >= 2) ? 768 : 0;
  BTwoF[(size_t)(l * 2 + side) * 393216 + (size_t)n * 1536 + base + k] =
      f2bf(Wo[(size_t)mat * 65536 + (size_t)k * 256 + n]);
}

// ===== Wc fold: BTwoF[sl][n][base + 256 + h*64+c] = sum_d We[c,h*32+d]*Wo[h*32+d,n] =====
__global__ __launch_bounds__(256)
void wc_k(const float* __restrict__ We, const float* __restrict__ Wo,
          unsigned short* __restrict__ BTwoF)
{
  const int mat = blockIdx.y;          // 0..7 = l*4+i
  const int j = blockIdx.x;            // 0..511 = h*64+c
  const int h = j >> 6, c = j & 63;
  const int n = threadIdx.x;           // 0..255
  const float* wep = We + (size_t)mat * 16384 + (size_t)c * 256 + h * 32;
  const float* wop = Wo + (size_t)mat * 65536 + (size_t)(h * 32) * 256 + n;
  float acc = 0.f;
#pragma unroll 8
  for (int d = 0; d < 32; ++d)
    acc += wep[d] * wop[(size_t)d * 256];
  const int l = mat >> 2, i = mat & 3;
  const int side = (i == 1 || i == 2) ? 1 : 0;
  const int base = (i >= 2) ? 768 : 0;
  BTwoF[(size_t)(l * 2 + side) * 393216 + (size_t)n * 1536 + base + 256 + j] = f2bf(acc);
}

// ===== per-dst online-softmax edge aggregation, 4 contexts via blockIdx.y =====
// 4-edge unrolled; ea loads are nontemporal (zero-reuse stream, keep L2 for kv).
__global__ __launch_bounds__(256)
void edge4_k(const int* __restrict__ o0, const int* __restrict__ o1,
             const int* __restrict__ o2, const int* __restrict__ o3,
             const int2* __restrict__ p0, const int2* __restrict__ p1,
             const int2* __restrict__ p2, const int2* __restrict__ p3,
             const float* __restrict__ e0, const float* __restrict__ e1,
             const float* __restrict__ e2, const float* __restrict__ e3,
             unsigned short* q0, unsigned short* q1,
             unsigned short* q2, unsigned short* q3,
             const unsigned short* __restrict__ k0, const unsigned short* __restrict__ k1,
             const unsigned short* __restrict__ k2, const unsigned short* __restrict__ k3,
             int Nn)
{
  const int y = blockIdx.y;
  const int* offs = (y == 0) ? o0 : (y == 1) ? o1 : (y == 2) ? o2 : o3;
  const int2* pairs = (y == 0) ? p0 : (y == 1) ? p1 : (y == 2) ? p2 : p3;
  const float* ea = (y == 0) ? e0 : (y == 1) ? e1 : (y == 2) ? e2 : e3;
  unsigned short* qTmsg = (y == 0) ? q0 : (y == 1) ? q1 : (y == 2) ? q2 : q3;
  const unsigned short* kv = (y == 0) ? k0 : (y == 1) ? k1 : (y == 2) ? k2 : k3;
  const int wv = (blockIdx.x * blockDim.x + threadIdx.x) >> 6;
  if (wv >= Nn) return;
  const int lane = threadIdx.x & 63;
  const int g = lane >> 3, p = lane & 7;
  const float scale = 0.17677669529663687f;
  const ushort4 qu = *(const ushort4*)(qTmsg + (size_t)wv * 1536 + lane * 4);
  const float qx = bf2f(qu.x), qy = bf2f(qu.y), qz = bf2f(qu.z), qw = bf2f(qu.w);
  const unsigned short* Tp = qTmsg + (size_t)wv * 1536 + 256 + g * 64 + p * 8;
  const ushort4 tu0 = *(const ushort4*)Tp;
  const ushort4 tu1 = *(const ushort4*)(Tp + 4);
  const float Ta0 = bf2f(tu0.x), Ta1 = bf2f(tu0.y), Ta2 = bf2f(tu0.z), Ta3 = bf2f(tu0.w);
  const float Tc0 = bf2f(tu1.x), Tc1 = bf2f(tu1.y), Tc2 = bf2f(tu1.z), Tc3 = bf2f(tu1.w);
  float m = -INFINITY, den = 0.f;
  float ax = 0.f, ay = 0.f, az = 0.f, aw = 0.f;
  float G[8] = {0,0,0,0,0,0,0,0};
  const int e0i = __builtin_amdgcn_readfirstlane(offs[wv]);
  const int e1i = __builtin_amdgcn_readfirstlane(offs[wv + 1]);
  for (int j = e0i; j < e1i; j += 4) {
    int2 pr[4];
    pr[0] = pairs[j];
#pragma unroll
    for (int u = 1; u < 4; ++u) pr[u] = (j + u < e1i) ? pairs[j + u] : pr[0];
    f32x4 ea0[4], ea1[4];
    short8 kvv[4];
#pragma unroll
    for (int u = 0; u < 4; ++u) {
      const f32x4* ep = (const f32x4*)(ea + (size_t)pr[u].x * 64 + p * 8);
      ea0[u] = __builtin_nontemporal_load(ep);
      ea1[u] = __builtin_nontemporal_load(ep + 1);
      kvv[u] = *(const short8*)(kv + (size_t)pr[u].y * 512 + lane * 8);
    }
    float s[4];
#pragma unroll
    for (int u = 0; u < 4; ++u) {
      float t = qx * bf2f((unsigned short)kvv[u][0]) + qy * bf2f((unsigned short)kvv[u][1])
              + qz * bf2f((unsigned short)kvv[u][2]) + qw * bf2f((unsigned short)kvv[u][3]);
      t += ea0[u][0]*Ta0 + ea0[u][1]*Ta1 + ea0[u][2]*Ta2 + ea0[u][3]*Ta3;
      t += ea1[u][0]*Tc0 + ea1[u][1]*Tc1 + ea1[u][2]*Tc2 + ea1[u][3]*Tc3;
      t += __shfl_xor(t, 1, 64);
      t += __shfl_xor(t, 2, 64);
      t += __shfl_xor(t, 4, 64);
      s[u] = (j + u < e1i) ? t * scale : -INFINITY;
    }
    const float mn = fmaxf(m, fmaxf(fmaxf(s[0], s[1]), fmaxf(s[2], s[3])));
    const float corr = __expf(m - mn);   // exp(-inf)=0 on first iteration
    m = mn;
    float w0 = __expf(s[0] - mn), w1 = __expf(s[1] - mn);
    float w2 = __expf(s[2] - mn), w3 = __expf(s[3] - mn);
    den = den * corr + w0 + w1 + w2 + w3;
    ax = ax * corr + w0*bf2f((unsigned short)kvv[0][4]) + w1*bf2f((unsigned short)kvv[1][4])
                   + w2*bf2f((unsigned short)kvv[2][4]) + w3*bf2f((unsigned short)kvv[3][4]);
    ay = ay * corr + w0*bf2f((unsigned short)kvv[0][5]) + w1*bf2f((unsigned short)kvv[1][5])
                   + w2*bf2f((unsigned short)kvv[2][5]) + w3*bf2f((unsigned short)kvv[3][5]);
    az = az * corr + w0*bf2f((unsigned short)kvv[0][6]) + w1*bf2f((unsigned short)kvv[1][6])
                   + w2*bf2f((unsigned short)kvv[2][6]) + w3*bf2f((unsigned short)kvv[3][6]);
    aw = aw * corr + w0*bf2f((unsigned short)kvv[0][7]) + w1*bf2f((unsigned short)kvv[1][7])
                   + w2*bf2f((unsigned short)kvv[2][7]) + w3*bf2f((unsigned short)kvv[3][7]);
#pragma unroll
    for (int i = 0; i < 4; ++i)
      G[i] = G[i] * corr + w0*ea0[0][i] + w1*ea0[1][i] + w2*ea0[2][i] + w3*ea0[3][i];
#pragma unroll
    for (int i = 0; i < 4; ++i)
      G[4 + i] = G[4 + i] * corr + w0*ea1[0][i] + w1*ea1[1][i] + w2*ea1[2][i] + w3*ea1[3][i];
  }
  const float inv = 1.f / (den + 1e-9f);
  ushort4 o;
  o.x = f2bf(ax * inv); o.y = f2bf(ay * inv);
  o.z = f2bf(az * inv); o.w = f2bf(aw * inv);
  *(ushort4*)(qTmsg + (size_t)wv * 1536 + lane * 4) = o;
  short8 gn;
#pragma unroll
  for (int i = 0; i < 8; ++i) gn[i] = (short)f2bf(G[i] * inv);
  *(short8*)(qTmsg + (size_t)wv * 1536 + 256 + g * 64 + p * 8) = gn;
}

// ===== residual add + LayerNorm on bf16 carry (L/R via blockIdx.y); add is bf16 =====
__global__ __launch_bounds__(256)
void add_ln2_k(unsigned short* __restrict__ xbL, const unsigned short* __restrict__ addL,
               unsigned short* __restrict__ xbR, const unsigned short* __restrict__ addR, int Nn)
{
  unsigned short* xb = blockIdx.y ? xbR : xbL;
  const unsigned short* add = blockIdx.y ? addR : addL;
  const int wv = (blockIdx.x * blockDim.x + threadIdx.x) >> 6;
  if (wv >= Nn) return;
  const int lane = threadIdx.x & 63;
  ushort4 xu = *(const ushort4*)(xb + (size_t)wv * 256 + lane * 4);
  ushort4 au = *(const ushort4*)(add + (size_t)wv * 256 + lane * 4);
  float4 y;
  y.x = bf2f(xu.x) + bf2f(au.x); y.y = bf2f(xu.y) + bf2f(au.y);
  y.z = bf2f(xu.z) + bf2f(au.z); y.w = bf2f(xu.w) + bf2f(au.w);
  float s = y.x + y.y + y.z + y.w;
#pragma unroll
  for (int msk = 1; msk < 64; msk <<= 1) s += __shfl_xor(s, msk, 64);
  const float mean = s * (1.f / 256.f);
  float4 d;
  d.x = y.x - mean; d.y = y.y - mean; d.z = y.z - mean; d.w = y.w - mean;
  float sq = d.x*d.x + d.y*d.y + d.z*d.z + d.w*d.w;
#pragma unroll
  for (int msk = 1; msk < 64; msk <<= 1) sq += __shfl_xor(sq, msk, 64);
  const float r = rsqrtf(sq * (1.f / 256.f) + 1e-5f);
  ushort4 ob;
  ob.x = f2bf(d.x * r); ob.y = f2bf(d.y * r);
  ob.z = f2bf(d.z * r); ob.w = f2bf(d.w * r);
  *(ushort4*)(xb + (size_t)wv * 256 + lane * 4) = ob;
}

// ===== init: f32 input -> bf16 carry (L/R via blockIdx.y) =====
__global__ void cvt_x2_k(const float* __restrict__ aL, unsigned short* __restrict__ xbL,
                         const float* __restrict__ aR, unsigned short* __restrict__ xbR, int n4)
{
  const float* a = blockIdx.y ? aR : aL;
  unsigned short* xb = blockIdx.y ? xbR : xbL;
  int i = blockIdx.x * 256 + threadIdx.x;
  if (i >= n4) return;
  float4 v = ((const float4*)a)[i];
  ushort4 b;
  b.x = f2bf(v.x); b.y = f2bf(v.y); b.z = f2bf(v.z); b.w = f2bf(v.w);
  ((ushort4*)xb)[i] = b;
}

// ===== CSR kernels =====
__global__ void zero4_k(int* p, int n) {
  int i = blockIdx.x * 256 + threadIdx.x;
  if (i < n) p[i] = 0;
}
__global__ void hist4_k(const int* d0, const int* d1, const int* d2, const int* d3,
                        int E0, int E1, int E2, int E3, int* cnt, int Nn) {
  const int s = blockIdx.y;
  const int* d = (s == 0) ? d0 : (s == 1) ? d1 : (s == 2) ? d2 : d3;
  const int E = (s == 0) ? E0 : (s == 1) ? E1 : (s == 2) ? E2 : E3;
  int e = blockIdx.x * 256 + threadIdx.x;
  if (e < E) atomicAdd(&cnt[s * Nn + d[e]], 1);
}
__global__ __launch_bounds__(256)
void scan4_k(const int* __restrict__ cnt, int* __restrict__ offs, int* __restrict__ cursor, int Nn)
{
  __shared__ int sums[256];
  const int s = blockIdx.x;
  const int t = threadIdx.x;
  const int* c = cnt + (size_t)s * Nn;
  int* o = offs + (size_t)s * (Nn + 1);
  int* cur = cursor + (size_t)s * Nn;
  const int chunk = (Nn + 255) / 256;
  const int base = t * chunk;
  int sl = 0;
  for (int i = 0; i < chunk; ++i) {
    int idx = base + i;
    if (idx < Nn) sl += c[idx];
  }
  sums[t] = sl;
  __syncthreads();
  for (int off = 1; off < 256; off <<= 1) {
    int val = (t >= off) ? sums[t - off] : 0;
    __syncthreads();
    sums[t] += val;
    __syncthreads();
  }
  int run = (t == 0) ? 0 : sums[t - 1];
  for (int i = 0; i < chunk; ++i) {
    int idx = base + i;
    if (idx < Nn) { o[idx] = run; cur[idx] = run; run += c[idx]; }
  }
  if (t == 255) o[Nn] = run;
}
__global__ void scatter4_k(const int* e0p, const int* e1p, const int* e2p, const int* e3p,
                           int E0, int E1, int E2, int E3, int* cursor,
                           int2* p0, int2* p1, int2* p2, int2* p3, int Nn) {
  const int s = blockIdx.y;
  const int* ei = (s == 0) ? e0p : (s == 1) ? e1p : (s == 2) ? e2p : e3p;
  int2* po = (s == 0) ? p0 : (s == 1) ? p1 : (s == 2) ? p2 : p3;
  const int E = (s == 0) ? E0 : (s == 1) ? E1 : (s == 2) ? E2 : E3;
  int e = blockIdx.x * 256 + threadIdx.x;
  if (e < E) {
    int pos = atomicAdd(&cursor[s * Nn + ei[E + e]], 1);
    po[pos] = make_int2(e, ei[e]);
  }
}

// ===== host orchestration =====
extern "C" void kernel_launch(void* const* d_in, const int* in_sizes, int n_in,
                              void* d_out, int out_size, void* d_ws, size_t ws_size,
                              hipStream_t stream)
{
  (void)n_in; (void)ws_size;
  const float* afl = (const float*)d_in[0];
  const float* afr = (const float*)d_in[1];
  const float* eaA[4] = {(const float*)d_in[2], (const float*)d_in[3],
                         (const float*)d_in[4], (const float*)d_in[5]};
  const int* eiA[4] = {(const int*)d_in[6], (const int*)d_in[7],
                       (const int*)d_in[8], (const int*)d_in[9]};
  const float* Wq  = (const float*)d_in[10];
  const float* Wk  = (const float*)d_in[11];
  const float* Wv  = (const float*)d_in[12];
  const float* We  = (const float*)d_in[13];
  const float* Wo  = (const float*)d_in[14];
  const float* fw1 = (const float*)d_in[15];
  const float* fb1 = (const float*)d_in[16];
  const float* fw2 = (const float*)d_in[17];
  const float* fb2 = (const float*)d_in[18];
  const float* hw1 = (const float*)d_in[19];
  const float* hb1 = (const float*)d_in[20];
  const float* hw2 = (const float*)d_in[21];
  const float* hb2 = (const float*)d_in[22];

  const int Nn = in_sizes[0] / 256;
  const int E[4] = {in_sizes[2] / 64, in_sizes[3] / 64, in_sizes[4] / 64, in_sizes[5] / 64};
  const int Mh = out_size / 14;
  const int astart = Nn - Mh;
  float* out = (float*)d_out;

  // workspace ~244 MB: xb 19 + agg 19 + qTmsg 113 + kv(4) 76 + weights 11 + csr/pairs 7
  char* wsp = (char*)d_ws;
  auto alloc = [&](size_t bytes) -> void* {
    void* pp = (void*)wsp;
    wsp += (bytes + 255) & ~(size_t)255;
    return pp;
  };
  unsigned short* xlb = (unsigned short*)alloc((size_t)Nn * 256 * 2);
  unsigned short* xrb = (unsigned short*)alloc((size_t)Nn * 256 * 2);
  unsigned short* aggLb = (unsigned short*)alloc((size_t)Nn * 256 * 2);
  unsigned short* aggRb = (unsigned short*)alloc((size_t)Nn * 256 * 2);
  unsigned short* qTmsgA = (unsigned short*)alloc((size_t)Nn * 1536 * 2);
  unsigned short* qTmsgB = (unsigned short*)alloc((size_t)Nn * 1536 * 2);
  unsigned short* kvSA = (unsigned short*)alloc((size_t)Nn * 512 * 2);  // ll kv; FFN hidden; head f32 scratch
  unsigned short* kvSB = (unsigned short*)alloc((size_t)Nn * 512 * 2);
  unsigned short* kvXL = (unsigned short*)alloc((size_t)Nn * 512 * 2);  // lr kv (from xl)
  unsigned short* kvXR = (unsigned short*)alloc((size_t)Nn * 512 * 2);  // rl kv (from xr)
  unsigned short* BTall = (unsigned short*)alloc((size_t)4 * 655360 * 2);
  unsigned short* BTwoF = (unsigned short*)alloc((size_t)4 * 256 * 1536 * 2);
  unsigned short* BTf1  = (unsigned short*)alloc((size_t)4 * 512 * 256 * 2);
  unsigned short* BTf2  = (unsigned short*)alloc((size_t)4 * 256 * 512 * 2);
  unsigned short* BTh1  = (unsigned short*)alloc((size_t)256 * 256 * 2);
  int* offs4 = (int*)alloc((size_t)4 * (Nn + 1) * 4);
  int* cnt4  = (int*)alloc((size_t)4 * Nn * 4);
  int* cur4  = (int*)alloc((size_t)4 * Nn * 4);
  int2* pairs[4];
  for (int s = 0; s < 4; ++s) pairs[s] = (int2*)alloc((size_t)E[s] * 8);

  const dim3 B256(256);
  const int wgNodes = (Nn * 64 + 255) / 256;
  int maxE = E[0];
  for (int s = 1; s < 4; ++s) if (E[s] > maxE) maxE = E[s];

  // ---- init xb, CSR pair lists ----
  cvt_x2_k<<<dim3((Nn * 64 + 255) / 256, 2), B256, 0, stream>>>(afl, xlb, afr, xrb, Nn * 64);
  zero4_k<<<dim3((4 * Nn + 255) / 256), B256, 0, stream>>>(cnt4, 4 * Nn);
  {
    dim3 gh((maxE + 255) / 256, 4);
    hist4_k<<<gh, B256, 0, stream>>>(eiA[0] + E[0], eiA[1] + E[1], eiA[2] + E[2], eiA[3] + E[3],
                                     E[0], E[1], E[2], E[3], cnt4, Nn);
    scan4_k<<<dim3(4), B256, 0, stream>>>(cnt4, offs4, cur4, Nn);
    scatter4_k<<<gh, B256, 0, stream>>>(eiA[0], eiA[1], eiA[2], eiA[3],
                                        E[0], E[1], E[2], E[3], cur4,
                                        pairs[0], pairs[1], pairs[2], pairs[3], Nn);
  }
  // ---- weight conversion ----
  {
    tc_all_k<<<dim3(256, 4, 6), B256, 0, stream>>>(Wq, Wk, Wv, BTall);
    wqe2_k<<<dim3(512, 4, 2), B256, 0, stream>>>(BTall, We);
    wo_tc_k<<<dim3(256, 8), B256, 0, stream>>>(Wo, BTwoF);
    wc_k<<<dim3(512, 8), B256, 0, stream>>>(We, Wo, BTwoF);
    tc_k<<<dim3((131072 + 255) / 256, 4), B256, 0, stream>>>(fw1, BTf1, 256, 512, 131072, 131072, 0, 256, 0);
    tc_k<<<dim3((131072 + 255) / 256, 4), B256, 0, stream>>>(fw2, BTf2, 512, 256, 131072, 131072, 0, 512, 0);
    tc_k<<<dim3((65536 + 255) / 256, 1), B256, 0, stream>>>(hw1, BTh1, 256, 256, 0, 0, 0, 256, 0);
  }

  auto mfma2 = [&](const unsigned short* A0, const unsigned short* A1, int lda,
                   const unsigned short* BT0, const unsigned short* BT1,
                   const float* bias0, const float* bias1,
                   float* Cf0, float* Cf1, int Sf, int ldf,
                   unsigned short* Cb10, unsigned short* Cb11, int S2, int ldb1,
                   unsigned short* Cb20, unsigned short* Cb21, int ldb2,
                   int M, int N, int K, bool biasf, bool gelu) {
    dim3 g(M / 128, N / 128, 2);
    if (biasf && gelu)
      gemm_mfma2_k<true, true ><<<g, B256, 0, stream>>>(A0, A1, lda, BT0, BT1, bias0, bias1,
          Cf0, Cf1, Sf, ldf, Cb10, Cb11, S2, ldb1, Cb20, Cb21, ldb2, M, N, K);
    else if (biasf)
      gemm_mfma2_k<true, false><<<g, B256, 0, stream>>>(A0, A1, lda, BT0, BT1, bias0, bias1,
          Cf0, Cf1, Sf, ldf, Cb10, Cb11, S2, ldb1, Cb20, Cb21, ldb2, M, N, K);
    else
      gemm_mfma2_k<false, false><<<g, B256, 0, stream>>>(A0, A1, lda, BT0, BT1, bias0, bias1,
          Cf0, Cf1, Sf, ldf, Cb10, Cb11, S2, ldb1, Cb20, Cb21, ldb2, M, N, K);
  };

  for (int l = 0; l < 2; ++l) {
    // 1) mega QKV: everything derived from xl (z0) and xr (z1)
    gemm_qkv_k<<<dim3(Nn / 128, 20, 2), B256, 0, stream>>>(
        xlb, xrb,
        BTall + (size_t)(l * 2 + 0) * 655360, BTall + (size_t)(l * 2 + 1) * 655360,
        qTmsgA, qTmsgB, kvSA, kvSB, kvXL, kvXR, Nn);
    // 2) all four edge aggregations in one dispatch
    edge4_k<<<dim3(wgNodes, 4), B256, 0, stream>>>(
        offs4, offs4 + (size_t)(Nn + 1), offs4 + (size_t)3 * (Nn + 1), offs4 + (size_t)2 * (Nn + 1),
        pairs[0], pairs[1], pairs[3], pairs[2],
        eaA[0], eaA[1], eaA[3], eaA[2],
        qTmsgA, qTmsgB, qTmsgA + 768, qTmsgB + 768,
        kvSA, kvSB, kvXR, kvXL, Nn);
    // 3) fused Wo: agg = [selfV|selfGn|crossV|crossGn] @ [Wo_s|Wc_s|Wo_c|Wc_c], K=1536
    mfma2(qTmsgA, qTmsgB, 1536, BTwoF + (size_t)(l*2+0)*393216, BTwoF + (size_t)(l*2+1)*393216,
          nullptr, nullptr, nullptr, nullptr, 0, 0, aggLb, aggRb, 256, 256,
          nullptr, nullptr, 0, Nn, 256, 1536, false, false);
    add_ln2_k<<<dim3(wgNodes, 2), B256, 0, stream>>>(xlb, aggLb, xrb, aggRb, Nn);
    // 4) FFN (L/R combined); kvS buffers reused as hidden (plain layout)
    const int fL = l * 2 + 0, fR = l * 2 + 1;
    mfma2(xlb, xrb, 256, BTf1 + (size_t)fL*131072, BTf1 + (size_t)fR*131072,
          fb1 + (size_t)fL*512, fb1 + (size_t)fR*512, nullptr, nullptr, 0, 0,
          kvSA, kvSB, 512, 512, nullptr, nullptr, 0, Nn, 512, 256, true, true);
    mfma2(kvSA, kvSB, 512, BTf2 + (size_t)fL*131072, BTf2 + (size_t)fR*131072,
          fb2 + (size_t)fL*256, fb2 + (size_t)fR*256, nullptr, nullptr, 0, 0,
          aggLb, aggRb, 256, 256, nullptr, nullptr, 0, Nn, 256, 512, true, false);
    add_ln2_k<<<dim3(wgNodes, 2), B256, 0, stream>>>(xlb, aggLb, xrb, aggRb, Nn);
  }
  // heads: gelu(x@hw1+hb1) -> f32 scratch (kvS), then @ hw2 + hb2
  float* h1L = (float*)kvSA;
  float* h1R = (float*)kvSB;
  mfma2(xlb + (size_t)astart * 256, xrb + (size_t)astart * 256, 256, BTh1, BTh1,
        hb1, hb1, h1L, h1R, 256, 256, nullptr, nullptr, 0, 0, nullptr, nullptr, 0,
        Mh, 256, 256, true, true);
  gemm_k2<true><<<dim3(Mh / 128, 1, 2), B256, 0, stream>>>(h1L, h1R, hw2, hb2,
                                                           out, out + (size_t)Mh * 7, Mh, 7, 256);
}

// Round 12
// 1057.126 us; speedup vs baseline: 1.0794x; 1.0794x over previous
//
#include <hip/hip_runtime.h>
#include <math.h>

typedef __attribute__((ext_vector_type(8))) short short8;
typedef __attribute__((ext_vector_type(4))) float f32x4;

__device__ __forceinline__ unsigned short f2bf(float f) {
  unsigned u = __builtin_bit_cast(unsigned, f);
  u += 0x7fff + ((u >> 16) & 1);
  return (unsigned short)(u >> 16);
}
__device__ __forceinline__ float bf2f(unsigned short h) {
  unsigned u = ((unsigned)h) << 16;
  return __builtin_bit_cast(float, u);
}
__device__ __forceinline__ float gelu_f(float x) {
  const float c0 = 0.7978845608028654f;
  return 0.5f * x * (1.0f + tanhf(c0 * (x + 0.044715f * x * x * x)));
}
// async global->LDS, 16B per lane; LDS dest = wave-uniform base + lane*16
__device__ __forceinline__ void gload16(const unsigned short* g, unsigned short* l) {
  __builtin_amdgcn_global_load_lds(
      (const __attribute__((address_space(1))) unsigned int*)g,
      (__attribute__((address_space(3))) unsigned int*)l, 16, 0, 0);
}
// interleave map for kv rows: k elem e -> (e>>2)*8 + (e&3); v elem e -> (e>>2)*8+4+(e&3)
__device__ __forceinline__ int ileave512(int cc) {
  const int base = (cc & 256) ? 4 : 0;
  const int c2 = cc & 255;
  return (c2 >> 2) * 8 + base + (c2 & 3);
}

// ===== mega QKV GEMM: per z-context computes everything derived from one x =====
// N=2560 col split: [0,768) qT self; [768,1280) kvS (interleaved);
// [1280,2048) qT cross; [2048,2560) kvX (interleaved).
__global__ __launch_bounds__(256)
void gemm_qkv_k(const unsigned short* __restrict__ A0, const unsigned short* __restrict__ A1,
                const unsigned short* __restrict__ BT0, const unsigned short* __restrict__ BT1,
                unsigned short* __restrict__ qT0, unsigned short* __restrict__ qT1,
                unsigned short* __restrict__ kvS0, unsigned short* __restrict__ kvS1,
                unsigned short* __restrict__ kvX0, unsigned short* __restrict__ kvX1,
                int M)
{
  const int z = blockIdx.z;
  const unsigned short* A  = z ? A1  : A0;
  const unsigned short* BT = z ? BT1 : BT0;
  unsigned short* qT  = z ? qT1  : qT0;
  unsigned short* kvS = z ? kvS1 : kvS0;
  unsigned short* kvX = z ? kvX1 : kvX0;
  const int K = 256, lda = 256;

  __shared__ __align__(16) unsigned short As[128 * 32];
  __shared__ __align__(16) unsigned short Bs[128 * 32];
  const int tid = threadIdx.x;
  const int bm = blockIdx.x * 128, bn = blockIdx.y * 128;
  const int lane = tid & 63, w = tid >> 6;
  const int wr = w >> 1, wc = w & 1;
  const int l15 = lane & 15, kg = lane >> 4;
  const int srow0 = w * 16 + (lane >> 2);
  const int srow1 = 64 + srow0;
  const int sslot = lane & 3;
  const int koff0 = (((sslot - (srow0 >> 1)) & 3)) * 8;
  const int koff1 = (((sslot - (srow1 >> 1)) & 3)) * 8;
  const unsigned short* gA0 = A + (size_t)(bm + srow0) * lda + koff0;
  const unsigned short* gA1 = A + (size_t)(bm + srow1) * lda + koff1;
  const unsigned short* gB0 = BT + (size_t)(bn + srow0) * K + koff0;
  const unsigned short* gB1 = BT + (size_t)(bn + srow1) * K + koff1;
  unsigned short* lA0 = As + w * 512;
  unsigned short* lA1 = As + 2048 + w * 512;
  unsigned short* lB0 = Bs + w * 512;
  unsigned short* lB1 = Bs + 2048 + w * 512;

  int roffA[4], roffB[4];
#pragma unroll
  for (int m = 0; m < 4; ++m) {
    int row = wr * 64 + m * 16 + l15;
    roffA[m] = row * 32 + ((kg + (row >> 1)) & 3) * 8;
  }
#pragma unroll
  for (int n = 0; n < 4; ++n) {
    int col = wc * 64 + n * 16 + l15;
    roffB[n] = col * 32 + ((kg + (col >> 1)) & 3) * 8;
  }

  f32x4 acc[4][4] = {};
  for (int k0 = 0; k0 < K; k0 += 32) {
    gload16(gA0 + k0, lA0);
    gload16(gA1 + k0, lA1);
    gload16(gB0 + k0, lB0);
    gload16(gB1 + k0, lB1);
    __syncthreads();
    short8 af[4], bfr[4];
#pragma unroll
    for (int m = 0; m < 4; ++m) af[m] = *(const short8*)(As + roffA[m]);
#pragma unroll
    for (int n = 0; n < 4; ++n) bfr[n] = *(const short8*)(Bs + roffB[n]);
#pragma unroll
    for (int m = 0; m < 4; ++m)
#pragma unroll
      for (int n = 0; n < 4; ++n)
        acc[m][n] = __builtin_amdgcn_mfma_f32_16x16x32_bf16(af[m], bfr[n], acc[m][n], 0, 0, 0);
    __syncthreads();
  }
#pragma unroll
  for (int m = 0; m < 4; ++m) {
#pragma unroll
    for (int n = 0; n < 4; ++n) {
      int col = bn + wc * 64 + n * 16 + l15;
      f32x4 v = acc[m][n];
#pragma unroll
      for (int r2 = 0; r2 < 4; ++r2) {
        int row = bm + wr * 64 + m * 16 + kg * 4 + r2;
        unsigned short bv = f2bf(v[r2]);
        if (col < 768) {
          qT[(size_t)row * 1536 + col] = bv;
        } else if (col < 1280) {
          kvS[(size_t)row * 512 + ileave512(col - 768)] = bv;
        } else if (col < 2048) {
          qT[(size_t)row * 1536 + 768 + (col - 1280)] = bv;
        } else {
          kvX[(size_t)row * 512 + ileave512(col - 2048)] = bv;
        }
      }
    }
  }
}

// ===== generic 2-context bf16 MFMA GEMM (blockIdx.z = L/R) =====
// col split: [0,Sf)->f32 Cf, [Sf,S2)->bf16 Cb1, [S2,N)->bf16 Cb2 (plain layouts).
template<bool BIAS, bool GELU>
__global__ __launch_bounds__(256)
void gemm_mfma2_k(const unsigned short* __restrict__ A0, const unsigned short* __restrict__ A1,
                  int lda,
                  const unsigned short* __restrict__ BT0, const unsigned short* __restrict__ BT1,
                  const float* __restrict__ bias0, const float* __restrict__ bias1,
                  float* __restrict__ Cf0, float* __restrict__ Cf1, int Sf, int ldf,
                  unsigned short* __restrict__ Cb10, unsigned short* __restrict__ Cb11,
                  int S2, int ldb1,
                  unsigned short* __restrict__ Cb20, unsigned short* __restrict__ Cb21, int ldb2,
                  int M, int N, int K)
{
  const int z = blockIdx.z;
  const unsigned short* A  = z ? A1  : A0;
  const unsigned short* BT = z ? BT1 : BT0;
  const float* bias        = z ? bias1 : bias0;
  float* Cf                = z ? Cf1 : Cf0;
  unsigned short* Cb1      = z ? Cb11 : Cb10;
  unsigned short* Cb2      = z ? Cb21 : Cb20;

  __shared__ __align__(16) unsigned short As[128 * 32];
  __shared__ __align__(16) unsigned short Bs[128 * 32];
  const int tid = threadIdx.x;
  const int bm = blockIdx.x * 128, bn = blockIdx.y * 128;
  const int lane = tid & 63, w = tid >> 6;
  const int wr = w >> 1, wc = w & 1;
  const int l15 = lane & 15, kg = lane >> 4;
  const int srow0 = w * 16 + (lane >> 2);
  const int srow1 = 64 + srow0;
  const int sslot = lane & 3;
  const int koff0 = (((sslot - (srow0 >> 1)) & 3)) * 8;
  const int koff1 = (((sslot - (srow1 >> 1)) & 3)) * 8;
  const unsigned short* gA0 = A + (size_t)(bm + srow0) * lda + koff0;
  const unsigned short* gA1 = A + (size_t)(bm + srow1) * lda + koff1;
  const unsigned short* gB0 = BT + (size_t)(bn + srow0) * K + koff0;
  const unsigned short* gB1 = BT + (size_t)(bn + srow1) * K + koff1;
  unsigned short* lA0 = As + w * 512;
  unsigned short* lA1 = As + 2048 + w * 512;
  unsigned short* lB0 = Bs + w * 512;
  unsigned short* lB1 = Bs + 2048 + w * 512;

  int roffA[4], roffB[4];
#pragma unroll
  for (int m = 0; m < 4; ++m) {
    int row = wr * 64 + m * 16 + l15;
    roffA[m] = row * 32 + ((kg + (row >> 1)) & 3) * 8;
  }
#pragma unroll
  for (int n = 0; n < 4; ++n) {
    int col = wc * 64 + n * 16 + l15;
    roffB[n] = col * 32 + ((kg + (col >> 1)) & 3) * 8;
  }

  f32x4 acc[4][4] = {};
  for (int k0 = 0; k0 < K; k0 += 32) {
    gload16(gA0 + k0, lA0);
    gload16(gA1 + k0, lA1);
    gload16(gB0 + k0, lB0);
    gload16(gB1 + k0, lB1);
    __syncthreads();
    short8 af[4], bfr[4];
#pragma unroll
    for (int m = 0; m < 4; ++m) af[m] = *(const short8*)(As + roffA[m]);
#pragma unroll
    for (int n = 0; n < 4; ++n) bfr[n] = *(const short8*)(Bs + roffB[n]);
#pragma unroll
    for (int m = 0; m < 4; ++m)
#pragma unroll
      for (int n = 0; n < 4; ++n)
        acc[m][n] = __builtin_amdgcn_mfma_f32_16x16x32_bf16(af[m], bfr[n], acc[m][n], 0, 0, 0);
    __syncthreads();
  }
#pragma unroll
  for (int m = 0; m < 4; ++m) {
#pragma unroll
    for (int n = 0; n < 4; ++n) {
      int col = bn + wc * 64 + n * 16 + l15;
      float bv = BIAS ? bias[col] : 0.f;
      f32x4 v = acc[m][n];
#pragma unroll
      for (int r2 = 0; r2 < 4; ++r2) {
        int row = bm + wr * 64 + m * 16 + kg * 4 + r2;
        float val = v[r2] + bv;
        if (GELU) val = gelu_f(val);
        if (col < Sf) {
          Cf[(size_t)row * ldf + col] = val;
        } else if (col < S2) {
          Cb1[(size_t)row * ldb1 + (col - Sf)] = f2bf(val);
        } else {
          Cb2[(size_t)row * ldb2 + (col - S2)] = f2bf(val);
        }
      }
    }
  }
}

// ===== f32 GEMM, 2-context (tiny N=7 head2) =====
template<bool BIAS>
__global__ __launch_bounds__(256)
void gemm_k2(const float* __restrict__ A0, const float* __restrict__ A1,
             const float* __restrict__ B, const float* __restrict__ bias,
             float* __restrict__ C0, float* __restrict__ C1,
             int M, int N, int K)
{
  const float* A = blockIdx.z ? A1 : A0;
  float* C = blockIdx.z ? C1 : C0;
  __shared__ float As[16][132];
  __shared__ float Bs[16][132];
  const int tid = threadIdx.x;
  const int tx = tid & 15, ty = tid >> 4;
  const int bm = blockIdx.x * 128;
  float acc[8][8];
#pragma unroll
  for (int i = 0; i < 8; ++i)
#pragma unroll
    for (int j = 0; j < 8; ++j) acc[i][j] = 0.f;
  const int ar = tid >> 1;
  const int ac = (tid & 1) * 8;
  const int br = tid >> 4;
  const int bc = (tid & 15) * 8;
  for (int k0 = 0; k0 < K; k0 += 16) {
    {
      float av[8] = {0,0,0,0,0,0,0,0};
      if (bm + ar < M) {
        const float* app = A + (size_t)(bm + ar) * K + (k0 + ac);
        float4 a0 = *(const float4*)app;
        float4 a1 = *(const float4*)(app + 4);
        av[0]=a0.x; av[1]=a0.y; av[2]=a0.z; av[3]=a0.w;
        av[4]=a1.x; av[5]=a1.y; av[6]=a1.z; av[7]=a1.w;
      }
#pragma unroll
      for (int i = 0; i < 8; ++i) As[ac + i][ar] = av[i];
    }
    {
      float bv[8] = {0,0,0,0,0,0,0,0};
      const float* bpp = B + (size_t)(k0 + br) * N + bc;
#pragma unroll
      for (int i = 0; i < 8; ++i) { if (bc + i < N) bv[i] = bpp[i]; }
#pragma unroll
      for (int i = 0; i < 8; ++i) Bs[br][bc + i] = bv[i];
    }
    __syncthreads();
#pragma unroll
    for (int kk = 0; kk < 16; ++kk) {
      float a[8], b[8];
      float4 t0 = *(const float4*)&As[kk][ty * 8];
      float4 t1 = *(const float4*)&As[kk][ty * 8 + 4];
      float4 u0 = *(const float4*)&Bs[kk][tx * 8];
      float4 u1 = *(const float4*)&Bs[kk][tx * 8 + 4];
      a[0]=t0.x;a[1]=t0.y;a[2]=t0.z;a[3]=t0.w;a[4]=t1.x;a[5]=t1.y;a[6]=t1.z;a[7]=t1.w;
      b[0]=u0.x;b[1]=u0.y;b[2]=u0.z;b[3]=u0.w;b[4]=u1.x;b[5]=u1.y;b[6]=u1.z;b[7]=u1.w;
#pragma unroll
      for (int i = 0; i < 8; ++i)
#pragma unroll
        for (int j = 0; j < 8; ++j)
          acc[i][j] = fmaf(a[i], b[j], acc[i][j]);
    }
    __syncthreads();
  }
#pragma unroll
  for (int i = 0; i < 8; ++i) {
    int row = bm + ty * 8 + i;
    if (row >= M) continue;
    int colg = tx * 8;
    float* cp = C + (size_t)row * N + colg;
#pragma unroll
    for (int j = 0; j < 8; ++j) {
      int cc = colg + j;
      if (cc < N) {
        float val = acc[i][j];
        if (BIAS) val += bias[cc];
        cp[j] = val;
      }
    }
  }
}

// ===== generic transpose+convert (FFN / head weights) =====
__global__ void tc_k(const float* __restrict__ in, unsigned short* __restrict__ out,
                     int K, int N, int inStride, int outStride, int rowOff, int totK, int kOff)
{
  const int mat = blockIdx.y;
  const int idx = blockIdx.x * 256 + threadIdx.x;
  if (idx >= N * K) return;
  const int n = idx / K, k = idx - n * K;
  out[(size_t)mat * outStride + (size_t)(rowOff + n) * totK + kOff + k] =
      f2bf(in[(size_t)mat * inStride + (size_t)k * N + n]);
}

// ===== mega-QKV weight pack: 6 parts x 4 slots (l,side) =====
__global__ void tc_all_k(const float* __restrict__ Wq, const float* __restrict__ Wk,
                         const float* __restrict__ Wv, unsigned short* __restrict__ BTall)
{
  const int part = blockIdx.z;
  const int slot = blockIdx.y;
  const int l = slot >> 1, zz = slot & 1;
  const int self = l * 4 + zz;
  const int crossq = l * 4 + (zz ? 2 : 3);
  const int crosskv = l * 4 + (zz ? 3 : 2);
  const float* in; int mat, rowOff;
  switch (part) {
    case 0: in = Wq; mat = self;    rowOff = 0;    break;
    case 1: in = Wk; mat = self;    rowOff = 768;  break;
    case 2: in = Wv; mat = self;    rowOff = 1024; break;
    case 3: in = Wq; mat = crossq;  rowOff = 1280; break;
    case 4: in = Wk; mat = crosskv; rowOff = 2048; break;
    default:in = Wv; mat = crosskv; rowOff = 2304; break;
  }
  const int idx = blockIdx.x * 256 + threadIdx.x;
  const int n = idx >> 8, k = idx & 255;
  BTall[(size_t)slot * 655360 + (size_t)(rowOff + n) * 256 + k] =
      f2bf(in[(size_t)mat * 65536 + (size_t)k * 256 + n]);
}

// ===== fused T-weights inside BTall (self rows 256..767; cross rows 1536..2047) =====
__global__ __launch_bounds__(256)
void wqe2_k(unsigned short* __restrict__ BTall, const float* __restrict__ We)
{
  const int which = blockIdx.z;        // 0 self, 1 cross
  const int slot = blockIdx.y;
  const int l = slot >> 1, zz = slot & 1;
  const int mat = which ? (l * 4 + (zz ? 2 : 3)) : (l * 4 + zz);
  const int baseQ = which ? 1280 : 0;
  const int baseT = which ? 1536 : 256;
  const int oc = blockIdx.x;           // 0..511 = head*64 + c
  const int g = oc >> 6, cc = oc & 63;
  const int kin = threadIdx.x;         // 0..255
  const float* wrow = We + (size_t)mat * 16384 + (size_t)cc * 256 + g * 32;
  const unsigned short* bq = BTall + (size_t)slot * 655360 + (size_t)(baseQ + g * 32) * 256 + kin;
  float acc = 0.f;
#pragma unroll 8
  for (int d = 0; d < 32; ++d)
    acc += bf2f(bq[(size_t)d * 256]) * wrow[d];
  BTall[(size_t)slot * 655360 + (size_t)(baseT + oc) * 256 + kin] = f2bf(acc);
}

// ===== fused Wo pack: BTwoF[sl][n][base + k] = Wo[mat][k][n] =====
__global__ void wo_tc_k(const float* __restrict__ Wo, unsigned short* __restrict__ BTwoF)
{
  const int mat = blockIdx.y;          // 0..7 = l*4+i
  const int idx = blockIdx.x * 256 + threadIdx.x;
  const int n = idx >> 8, k = idx & 255;
  const int l = mat >> 2, i = mat & 3;
  const int side = (i == 1 || i == 2) ? 1 : 0;
  const int base = (i >= 2) ? 768 : 0;
  BTwoF[(size_t)(l * 2 + side) * 393216 + (size_t)n * 1536 + base + k] =
      f2bf(Wo[(size_t)mat * 65536 + (size_t)k * 256 + n]);
}

// ===== Wc fold: BTwoF[sl][n][base + 256 + h*64+c] = sum_d We[c,h*32+d]*Wo[h*32+d,n] =====
__global__ __launch_bounds__(256)
void wc_k(const float* __restrict__ We, const float* __restrict__ Wo,
          unsigned short* __restrict__ BTwoF)
{
  const int mat = blockIdx.y;          // 0..7 = l*4+i
  const int j = blockIdx.x;            // 0..511 = h*64+c
  const int h = j >> 6, c = j & 63;
  const int n = threadIdx.x;           // 0..255
  const float* wep = We + (size_t)mat * 16384 + (size_t)c * 256 + h * 32;
  const float* wop = Wo + (size_t)mat * 65536 + (size_t)(h * 32) * 256 + n;
  float acc = 0.f;
#pragma unroll 8
  for (int d = 0; d < 32; ++d)
    acc += wep[d] * wop[(size_t)d * 256];
  const int l = mat >> 2, i = mat & 3;
  const int side = (i == 1 || i == 2) ? 1 : 0;
  const int base = (i >= 2) ? 768 : 0;
  BTwoF[(size_t)(l * 2 + side) * 393216 + (size_t)n * 1536 + base + 256 + j] = f2bf(acc);
}

// ===== per-dst online-softmax edge aggregation, 4 contexts via blockIdx.y =====
// 2-edge loop (R10 structure); ea loads nontemporal (zero-reuse stream).
__global__ __launch_bounds__(256)
void edge4_k(const int* __restrict__ o0, const int* __restrict__ o1,
             const int* __restrict__ o2, const int* __restrict__ o3,
             const int2* __restrict__ p0, const int2* __restrict__ p1,
             const int2* __restrict__ p2, const int2* __restrict__ p3,
             const float* __restrict__ e0, const float* __restrict__ e1,
             const float* __restrict__ e2, const float* __restrict__ e3,
             unsigned short* q0, unsigned short* q1,
             unsigned short* q2, unsigned short* q3,
             const unsigned short* __restrict__ k0, const unsigned short* __restrict__ k1,
             const unsigned short* __restrict__ k2, const unsigned short* __restrict__ k3,
             int Nn)
{
  const int y = blockIdx.y;
  const int* offs = (y == 0) ? o0 : (y == 1) ? o1 : (y == 2) ? o2 : o3;
  const int2* pairs = (y == 0) ? p0 : (y == 1) ? p1 : (y == 2) ? p2 : p3;
  const float* ea = (y == 0) ? e0 : (y == 1) ? e1 : (y == 2) ? e2 : e3;
  unsigned short* qTmsg = (y == 0) ? q0 : (y == 1) ? q1 : (y == 2) ? q2 : q3;
  const unsigned short* kv = (y == 0) ? k0 : (y == 1) ? k1 : (y == 2) ? k2 : k3;
  const int wv = (blockIdx.x * blockDim.x + threadIdx.x) >> 6;
  if (wv >= Nn) return;
  const int lane = threadIdx.x & 63;
  const int g = lane >> 3, p = lane & 7;
  const float scale = 0.17677669529663687f;
  const ushort4 qu = *(const ushort4*)(qTmsg + (size_t)wv * 1536 + lane * 4);
  const float qx = bf2f(qu.x), qy = bf2f(qu.y), qz = bf2f(qu.z), qw = bf2f(qu.w);
  const unsigned short* Tp = qTmsg + (size_t)wv * 1536 + 256 + g * 64 + p * 8;
  const ushort4 tu0 = *(const ushort4*)Tp;
  const ushort4 tu1 = *(const ushort4*)(Tp + 4);
  const float Ta0 = bf2f(tu0.x), Ta1 = bf2f(tu0.y), Ta2 = bf2f(tu0.z), Ta3 = bf2f(tu0.w);
  const float Tc0 = bf2f(tu1.x), Tc1 = bf2f(tu1.y), Tc2 = bf2f(tu1.z), Tc3 = bf2f(tu1.w);
  float m = -INFINITY, den = 0.f;
  float ax = 0.f, ay = 0.f, az = 0.f, aw = 0.f;
  float G[8] = {0,0,0,0,0,0,0,0};
  const int e0i = __builtin_amdgcn_readfirstlane(offs[wv]);
  const int e1i = __builtin_amdgcn_readfirstlane(offs[wv + 1]);
  for (int j = e0i; j < e1i; j += 2) {
    const bool hasB = (j + 1) < e1i;
    const int2 prA = pairs[j];
    const int2 prB = hasB ? pairs[j + 1] : prA;
    const f32x4* epA = (const f32x4*)(ea + (size_t)prA.x * 64 + p * 8);
    const f32x4* epB = (const f32x4*)(ea + (size_t)prB.x * 64 + p * 8);
    const f32x4 a0 = __builtin_nontemporal_load(epA);
    const f32x4 a1 = __builtin_nontemporal_load(epA + 1);
    const f32x4 b0 = __builtin_nontemporal_load(epB);
    const f32x4 b1 = __builtin_nontemporal_load(epB + 1);
    const short8 kvA = *(const short8*)(kv + (size_t)prA.y * 512 + lane * 8);
    const short8 kvB = *(const short8*)(kv + (size_t)prB.y * 512 + lane * 8);
    float pA = qx * bf2f((unsigned short)kvA[0]) + qy * bf2f((unsigned short)kvA[1])
             + qz * bf2f((unsigned short)kvA[2]) + qw * bf2f((unsigned short)kvA[3]);
    pA += a0[0]*Ta0 + a0[1]*Ta1 + a0[2]*Ta2 + a0[3]*Ta3;
    pA += a1[0]*Tc0 + a1[1]*Tc1 + a1[2]*Tc2 + a1[3]*Tc3;
    float pB = qx * bf2f((unsigned short)kvB[0]) + qy * bf2f((unsigned short)kvB[1])
             + qz * bf2f((unsigned short)kvB[2]) + qw * bf2f((unsigned short)kvB[3]);
    pB += b0[0]*Ta0 + b0[1]*Ta1 + b0[2]*Ta2 + b0[3]*Ta3;
    pB += b1[0]*Tc0 + b1[1]*Tc1 + b1[2]*Tc2 + b1[3]*Tc3;
    pA += __shfl_xor(pA, 1, 64); pA += __shfl_xor(pA, 2, 64); pA += __shfl_xor(pA, 4, 64);
    pB += __shfl_xor(pB, 1, 64); pB += __shfl_xor(pB, 2, 64); pB += __shfl_xor(pB, 4, 64);
    const float sA = pA * scale;
    const float sB = hasB ? pB * scale : -INFINITY;
    const float mn = fmaxf(m, fmaxf(sA, sB));
    const float corr = __expf(m - mn);   // exp(-inf)=0 on first iteration
    const float wA = __expf(sA - mn);
    const float wB = __expf(sB - mn);
    m = mn;
    den = den * corr + wA + wB;
    ax = ax * corr + wA * bf2f((unsigned short)kvA[4]) + wB * bf2f((unsigned short)kvB[4]);
    ay = ay * corr + wA * bf2f((unsigned short)kvA[5]) + wB * bf2f((unsigned short)kvB[5]);
    az = az * corr + wA * bf2f((unsigned short)kvA[6]) + wB * bf2f((unsigned short)kvB[6]);
    aw = aw * corr + wA * bf2f((unsigned short)kvA[7]) + wB * bf2f((unsigned short)kvB[7]);
    G[0] = G[0] * corr + wA * a0[0] + wB * b0[0];
    G[1] = G[1] * corr + wA * a0[1] + wB * b0[1];
    G[2] = G[2] * corr + wA * a0[2] + wB * b0[2];
    G[3] = G[3] * corr + wA * a0[3] + wB * b0[3];
    G[4] = G[4] * corr + wA * a1[0] + wB * b1[0];
    G[5] = G[5] * corr + wA * a1[1] + wB * b1[1];
    G[6] = G[6] * corr + wA * a1[2] + wB * b1[2];
    G[7] = G[7] * corr + wA * a1[3] + wB * b1[3];
  }
  const float inv = 1.f / (den + 1e-9f);
  ushort4 o;
  o.x = f2bf(ax * inv); o.y = f2bf(ay * inv);
  o.z = f2bf(az * inv); o.w = f2bf(aw * inv);
  *(ushort4*)(qTmsg + (size_t)wv * 1536 + lane * 4) = o;
  short8 gn;
#pragma unroll
  for (int i = 0; i < 8; ++i) gn[i] = (short)f2bf(G[i] * inv);
  *(short8*)(qTmsg + (size_t)wv * 1536 + 256 + g * 64 + p * 8) = gn;
}

// ===== residual add + LayerNorm on bf16 carry (L/R via blockIdx.y); add is bf16 =====
__global__ __launch_bounds__(256)
void add_ln2_k(unsigned short* __restrict__ xbL, const unsigned short* __restrict__ addL,
               unsigned short* __restrict__ xbR, const unsigned short* __restrict__ addR, int Nn)
{
  unsigned short* xb = blockIdx.y ? xbR : xbL;
  const unsigned short* add = blockIdx.y ? addR : addL;
  const int wv = (blockIdx.x * blockDim.x + threadIdx.x) >> 6;
  if (wv >= Nn) return;
  const int lane = threadIdx.x & 63;
  ushort4 xu = *(const ushort4*)(xb + (size_t)wv * 256 + lane * 4);
  ushort4 au = *(const ushort4*)(add + (size_t)wv * 256 + lane * 4);
  float4 y;
  y.x = bf2f(xu.x) + bf2f(au.x); y.y = bf2f(xu.y) + bf2f(au.y);
  y.z = bf2f(xu.z) + bf2f(au.z); y.w = bf2f(xu.w) + bf2f(au.w);
  float s = y.x + y.y + y.z + y.w;
#pragma unroll
  for (int msk = 1; msk < 64; msk <<= 1) s += __shfl_xor(s, msk, 64);
  const float mean = s * (1.f / 256.f);
  float4 d;
  d.x = y.x - mean; d.y = y.y - mean; d.z = y.z - mean; d.w = y.w - mean;
  float sq = d.x*d.x + d.y*d.y + d.z*d.z + d.w*d.w;
#pragma unroll
  for (int msk = 1; msk < 64; msk <<= 1) sq += __shfl_xor(sq, msk, 64);
  const float r = rsqrtf(sq * (1.f / 256.f) + 1e-5f);
  ushort4 ob;
  ob.x = f2bf(d.x * r); ob.y = f2bf(d.y * r);
  ob.z = f2bf(d.z * r); ob.w = f2bf(d.w * r);
  *(ushort4*)(xb + (size_t)wv * 256 + lane * 4) = ob;
}

// ===== init: f32 input -> bf16 carry (L/R via blockIdx.y) =====
__global__ void cvt_x2_k(const float* __restrict__ aL, unsigned short* __restrict__ xbL,
                         const float* __restrict__ aR, unsigned short* __restrict__ xbR, int n4)
{
  const float* a = blockIdx.y ? aR : aL;
  unsigned short* xb = blockIdx.y ? xbR : xbL;
  int i = blockIdx.x * 256 + threadIdx.x;
  if (i >= n4) return;
  float4 v = ((const float4*)a)[i];
  ushort4 b;
  b.x = f2bf(v.x); b.y = f2bf(v.y); b.z = f2bf(v.z); b.w = f2bf(v.w);
  ((ushort4*)xb)[i] = b;
}

// ===== CSR kernels =====
__global__ void zero4_k(int* p, int n) {
  int i = blockIdx.x * 256 + threadIdx.x;
  if (i < n) p[i] = 0;
}
__global__ void hist4_k(const int* d0, const int* d1, const int* d2, const int* d3,
                        int E0, int E1, int E2, int E3, int* cnt, int Nn) {
  const int s = blockIdx.y;
  const int* d = (s == 0) ? d0 : (s == 1) ? d1 : (s == 2) ? d2 : d3;
  const int E = (s == 0) ? E0 : (s == 1) ? E1 : (s == 2) ? E2 : E3;
  int e = blockIdx.x * 256 + threadIdx.x;
  if (e < E) atomicAdd(&cnt[s * Nn + d[e]], 1);
}
__global__ __launch_bounds__(256)
void scan4_k(const int* __restrict__ cnt, int* __restrict__ offs, int* __restrict__ cursor, int Nn)
{
  __shared__ int sums[256];
  const int s = blockIdx.x;
  const int t = threadIdx.x;
  const int* c = cnt + (size_t)s * Nn;
  int* o = offs + (size_t)s * (Nn + 1);
  int* cur = cursor + (size_t)s * Nn;
  const int chunk = (Nn + 255) / 256;
  const int base = t * chunk;
  int sl = 0;
  for (int i = 0; i < chunk; ++i) {
    int idx = base + i;
    if (idx < Nn) sl += c[idx];
  }
  sums[t] = sl;
  __syncthreads();
  for (int off = 1; off < 256; off <<= 1) {
    int val = (t >= off) ? sums[t - off] : 0;
    __syncthreads();
    sums[t] += val;
    __syncthreads();
  }
  int run = (t == 0) ? 0 : sums[t - 1];
  for (int i = 0; i < chunk; ++i) {
    int idx = base + i;
    if (idx < Nn) { o[idx] = run; cur[idx] = run; run += c[idx]; }
  }
  if (t == 255) o[Nn] = run;
}
__global__ void scatter4_k(const int* e0p, const int* e1p, const int* e2p, const int* e3p,
                           int E0, int E1, int E2, int E3, int* cursor,
                           int2* p0, int2* p1, int2* p2, int2* p3, int Nn) {
  const int s = blockIdx.y;
  const int* ei = (s == 0) ? e0p : (s == 1) ? e1p : (s == 2) ? e2p : e3p;
  int2* po = (s == 0) ? p0 : (s == 1) ? p1 : (s == 2) ? p2 : p3;
  const int E = (s == 0) ? E0 : (s == 1) ? E1 : (s == 2) ? E2 : E3;
  int e = blockIdx.x * 256 + threadIdx.x;
  if (e < E) {
    int pos = atomicAdd(&cursor[s * Nn + ei[E + e]], 1);
    po[pos] = make_int2(e, ei[e]);
  }
}

// ===== host orchestration =====
extern "C" void kernel_launch(void* const* d_in, const int* in_sizes, int n_in,
                              void* d_out, int out_size, void* d_ws, size_t ws_size,
                              hipStream_t stream)
{
  (void)n_in; (void)ws_size;
  const float* afl = (const float*)d_in[0];
  const float* afr = (const float*)d_in[1];
  const float* eaA[4] = {(const float*)d_in[2], (const float*)d_in[3],
                         (const float*)d_in[4], (const float*)d_in[5]};
  const int* eiA[4] = {(const int*)d_in[6], (const int*)d_in[7],
                       (const int*)d_in[8], (const int*)d_in[9]};
  const float* Wq  = (const float*)d_in[10];
  const float* Wk  = (const float*)d_in[11];
  const float* Wv  = (const float*)d_in[12];
  const float* We  = (const float*)d_in[13];
  const float* Wo  = (const float*)d_in[14];
  const float* fw1 = (const float*)d_in[15];
  const float* fb1 = (const float*)d_in[16];
  const float* fw2 = (const float*)d_in[17];
  const float* fb2 = (const float*)d_in[18];
  const float* hw1 = (const float*)d_in[19];
  const float* hb1 = (const float*)d_in[20];
  const float* hw2 = (const float*)d_in[21];
  const float* hb2 = (const float*)d_in[22];

  const int Nn = in_sizes[0] / 256;
  const int E[4] = {in_sizes[2] / 64, in_sizes[3] / 64, in_sizes[4] / 64, in_sizes[5] / 64};
  const int Mh = out_size / 14;
  const int astart = Nn - Mh;
  float* out = (float*)d_out;

  // workspace ~244 MB: xb 19 + agg 19 + qTmsg 113 + kv(4) 76 + weights 11 + csr/pairs 7
  char* wsp = (char*)d_ws;
  auto alloc = [&](size_t bytes) -> void* {
    void* pp = (void*)wsp;
    wsp += (bytes + 255) & ~(size_t)255;
    return pp;
  };
  unsigned short* xlb = (unsigned short*)alloc((size_t)Nn * 256 * 2);
  unsigned short* xrb = (unsigned short*)alloc((size_t)Nn * 256 * 2);
  unsigned short* aggLb = (unsigned short*)alloc((size_t)Nn * 256 * 2);
  unsigned short* aggRb = (unsigned short*)alloc((size_t)Nn * 256 * 2);
  unsigned short* qTmsgA = (unsigned short*)alloc((size_t)Nn * 1536 * 2);
  unsigned short* qTmsgB = (unsigned short*)alloc((size_t)Nn * 1536 * 2);
  unsigned short* kvSA = (unsigned short*)alloc((size_t)Nn * 512 * 2);  // ll kv; FFN hidden; head f32 scratch
  unsigned short* kvSB = (unsigned short*)alloc((size_t)Nn * 512 * 2);
  unsigned short* kvXL = (unsigned short*)alloc((size_t)Nn * 512 * 2);  // lr kv (from xl)
  unsigned short* kvXR = (unsigned short*)alloc((size_t)Nn * 512 * 2);  // rl kv (from xr)
  unsigned short* BTall = (unsigned short*)alloc((size_t)4 * 655360 * 2);
  unsigned short* BTwoF = (unsigned short*)alloc((size_t)4 * 256 * 1536 * 2);
  unsigned short* BTf1  = (unsigned short*)alloc((size_t)4 * 512 * 256 * 2);
  unsigned short* BTf2  = (unsigned short*)alloc((size_t)4 * 256 * 512 * 2);
  unsigned short* BTh1  = (unsigned short*)alloc((size_t)256 * 256 * 2);
  int* offs4 = (int*)alloc((size_t)4 * (Nn + 1) * 4);
  int* cnt4  = (int*)alloc((size_t)4 * Nn * 4);
  int* cur4  = (int*)alloc((size_t)4 * Nn * 4);
  int2* pairs[4];
  for (int s = 0; s < 4; ++s) pairs[s] = (int2*)alloc((size_t)E[s] * 8);

  const dim3 B256(256);
  const int wgNodes = (Nn * 64 + 255) / 256;
  int maxE = E[0];
  for (int s = 1; s < 4; ++s) if (E[s] > maxE) maxE = E[s];

  // ---- init xb, CSR pair lists ----
  cvt_x2_k<<<dim3((Nn * 64 + 255) / 256, 2), B256, 0, stream>>>(afl, xlb, afr, xrb, Nn * 64);
  zero4_k<<<dim3((4 * Nn + 255) / 256), B256, 0, stream>>>(cnt4, 4 * Nn);
  {
    dim3 gh((maxE + 255) / 256, 4);
    hist4_k<<<gh, B256, 0, stream>>>(eiA[0] + E[0], eiA[1] + E[1], eiA[2] + E[2], eiA[3] + E[3],
                                     E[0], E[1], E[2], E[3], cnt4, Nn);
    scan4_k<<<dim3(4), B256, 0, stream>>>(cnt4, offs4, cur4, Nn);
    scatter4_k<<<gh, B256, 0, stream>>>(eiA[0], eiA[1], eiA[2], eiA[3],
                                        E[0], E[1], E[2], E[3], cur4,
                                        pairs[0], pairs[1], pairs[2], pairs[3], Nn);
  }
  // ---- weight conversion ----
  {
    tc_all_k<<<dim3(256, 4, 6), B256, 0, stream>>>(Wq, Wk, Wv, BTall);
    wqe2_k<<<dim3(512, 4, 2), B256, 0, stream>>>(BTall, We);
    wo_tc_k<<<dim3(256, 8), B256, 0, stream>>>(Wo, BTwoF);
    wc_k<<<dim3(512, 8), B256, 0, stream>>>(We, Wo, BTwoF);
    tc_k<<<dim3((131072 + 255) / 256, 4), B256, 0, stream>>>(fw1, BTf1, 256, 512, 131072, 131072, 0, 256, 0);
    tc_k<<<dim3((131072 + 255) / 256, 4), B256, 0, stream>>>(fw2, BTf2, 512, 256, 131072, 131072, 0, 512, 0);
    tc_k<<<dim3((65536 + 255) / 256, 1), B256, 0, stream>>>(hw1, BTh1, 256, 256, 0, 0, 0, 256, 0);
  }

  auto mfma2 = [&](const unsigned short* A0, const unsigned short* A1, int lda,
                   const unsigned short* BT0, const unsigned short* BT1,
                   const float* bias0, const float* bias1,
                   float* Cf0, float* Cf1, int Sf, int ldf,
                   unsigned short* Cb10, unsigned short* Cb11, int S2, int ldb1,
                   unsigned short* Cb20, unsigned short* Cb21, int ldb2,
                   int M, int N, int K, bool biasf, bool gelu) {
    dim3 g(M / 128, N / 128, 2);
    if (biasf && gelu)
      gemm_mfma2_k<true, true ><<<g, B256, 0, stream>>>(A0, A1, lda, BT0, BT1, bias0, bias1,
          Cf0, Cf1, Sf, ldf, Cb10, Cb11, S2, ldb1, Cb20, Cb21, ldb2, M, N, K);
    else if (biasf)
      gemm_mfma2_k<true, false><<<g, B256, 0, stream>>>(A0, A1, lda, BT0, BT1, bias0, bias1,
          Cf0, Cf1, Sf, ldf, Cb10, Cb11, S2, ldb1, Cb20, Cb21, ldb2, M, N, K);
    else
      gemm_mfma2_k<false, false><<<g, B256, 0, stream>>>(A0, A1, lda, BT0, BT1, bias0, bias1,
          Cf0, Cf1, Sf, ldf, Cb10, Cb11, S2, ldb1, Cb20, Cb21, ldb2, M, N, K);
  };

  for (int l = 0; l < 2; ++l) {
    // 1) mega QKV: everything derived from xl (z0) and xr (z1)
    gemm_qkv_k<<<dim3(Nn / 128, 20, 2), B256, 0, stream>>>(
        xlb, xrb,
        BTall + (size_t)(l * 2 + 0) * 655360, BTall + (size_t)(l * 2 + 1) * 655360,
        qTmsgA, qTmsgB, kvSA, kvSB, kvXL, kvXR, Nn);
    // 2) all four edge aggregations in one dispatch
    edge4_k<<<dim3(wgNodes, 4), B256, 0, stream>>>(
        offs4, offs4 + (size_t)(Nn + 1), offs4 + (size_t)3 * (Nn + 1), offs4 + (size_t)2 * (Nn + 1),
        pairs[0], pairs[1], pairs[3], pairs[2],
        eaA[0], eaA[1], eaA[3], eaA[2],
        qTmsgA, qTmsgB, qTmsgA + 768, qTmsgB + 768,
        kvSA, kvSB, kvXR, kvXL, Nn);
    // 3) fused Wo: agg = [selfV|selfGn|crossV|crossGn] @ [Wo_s|Wc_s|Wo_c|Wc_c], K=1536
    mfma2(qTmsgA, qTmsgB, 1536, BTwoF + (size_t)(l*2+0)*393216, BTwoF + (size_t)(l*2+1)*393216,
          nullptr, nullptr, nullptr, nullptr, 0, 0, aggLb, aggRb, 256, 256,
          nullptr, nullptr, 0, Nn, 256, 1536, false, false);
    add_ln2_k<<<dim3(wgNodes, 2), B256, 0, stream>>>(xlb, aggLb, xrb, aggRb, Nn);
    // 4) FFN (L/R combined); kvS buffers reused as hidden (plain layout)
    const int fL = l * 2 + 0, fR = l * 2 + 1;
    mfma2(xlb, xrb, 256, BTf1 + (size_t)fL*131072, BTf1 + (size_t)fR*131072,
          fb1 + (size_t)fL*512, fb1 + (size_t)fR*512, nullptr, nullptr, 0, 0,
          kvSA, kvSB, 512, 512, nullptr, nullptr, 0, Nn, 512, 256, true, true);
    mfma2(kvSA, kvSB, 512, BTf2 + (size_t)fL*131072, BTf2 + (size_t)fR*131072,
          fb2 + (size_t)fL*256, fb2 + (size_t)fR*256, nullptr, nullptr, 0, 0,
          aggLb, aggRb, 256, 256, nullptr, nullptr, 0, Nn, 256, 512, true, false);
    add_ln2_k<<<dim3(wgNodes, 2), B256, 0, stream>>>(xlb, aggLb, xrb, aggRb, Nn);
  }
  // heads: gelu(x@hw1+hb1) -> f32 scratch (kvS), then @ hw2 + hb2
  float* h1L = (float*)kvSA;
  float* h1R = (float*)kvSB;
  mfma2(xlb + (size_t)astart * 256, xrb + (size_t)astart * 256, 256, BTh1, BTh1,
        hb1, hb1, h1L, h1R, 256, 256, nullptr, nullptr, 0, 0, nullptr, nullptr, 0,
        Mh, 256, 256, true, true);
  gemm_k2<true><<<dim3(Mh / 128, 1, 2), B256, 0, stream>>>(h1L, h1R, hw2, hb2,
                                                           out, out + (size_t)Mh * 7, Mh, 7, 256);
}

// Round 13
// 1029.002 us; speedup vs baseline: 1.1089x; 1.0273x over previous
//
#include <hip/hip_runtime.h>
#include <math.h>

typedef __attribute__((ext_vector_type(8))) short short8;
typedef __attribute__((ext_vector_type(4))) float f32x4;

__device__ __forceinline__ unsigned short f2bf(float f) {
  unsigned u = __builtin_bit_cast(unsigned, f);
  u += 0x7fff + ((u >> 16) & 1);
  return (unsigned short)(u >> 16);
}
__device__ __forceinline__ float bf2f(unsigned short h) {
  unsigned u = ((unsigned)h) << 16;
  return __builtin_bit_cast(float, u);
}
__device__ __forceinline__ float gelu_f(float x) {
  const float c0 = 0.7978845608028654f;
  return 0.5f * x * (1.0f + tanhf(c0 * (x + 0.044715f * x * x * x)));
}
// async global->LDS, 16B per lane; LDS dest = wave-uniform base + lane*16
__device__ __forceinline__ void gload16(const unsigned short* g, unsigned short* l) {
  __builtin_amdgcn_global_load_lds(
      (const __attribute__((address_space(1))) unsigned int*)g,
      (__attribute__((address_space(3))) unsigned int*)l, 16, 0, 0);
}
// interleave map for kv rows: k elem e -> (e>>2)*8 + (e&3); v elem e -> (e>>2)*8+4+(e&3)
__device__ __forceinline__ int ileave512(int cc) {
  const int base = (cc & 256) ? 4 : 0;
  const int c2 = cc & 255;
  return (c2 >> 2) * 8 + base + (c2 & 3);
}

// ===== shared double-buffered K-loop with counted vmcnt (T3-lite + T4) =====
// As/Bs are [2*4096] ushort. Next tile's 4 loads stay in flight across the
// barrier (vmcnt(4)); their latency hides under current tile's ds_read+MFMA.
__device__ __forceinline__ void kloop_db(
    const unsigned short* gA0, const unsigned short* gA1,
    const unsigned short* gB0, const unsigned short* gB1,
    unsigned short* As, unsigned short* Bs,
    int lo0, int lo1, const int* roffA, const int* roffB,
    f32x4 (&acc)[4][4], int K)
{
  gload16(gA0, As + lo0);
  gload16(gA1, As + lo1);
  gload16(gB0, Bs + lo0);
  gload16(gB1, Bs + lo1);
  int cur = 0;
  for (int k0 = 32; k0 < K; k0 += 32) {
    const int nb = (cur ^ 1) * 4096;
    gload16(gA0 + k0, As + nb + lo0);
    gload16(gA1 + k0, As + nb + lo1);
    gload16(gB0 + k0, Bs + nb + lo0);
    gload16(gB1 + k0, Bs + nb + lo1);
    __builtin_amdgcn_sched_barrier(0);
    asm volatile("s_waitcnt vmcnt(4)" ::: "memory");   // old 4 done; new 4 in flight
    __builtin_amdgcn_s_barrier();
    __builtin_amdgcn_sched_barrier(0);
    const int cb = cur * 4096;
    short8 af[4], bfr[4];
#pragma unroll
    for (int m = 0; m < 4; ++m) af[m] = *(const short8*)(As + cb + roffA[m]);
#pragma unroll
    for (int n = 0; n < 4; ++n) bfr[n] = *(const short8*)(Bs + cb + roffB[n]);
#pragma unroll
    for (int m = 0; m < 4; ++m)
#pragma unroll
      for (int n = 0; n < 4; ++n)
        acc[m][n] = __builtin_amdgcn_mfma_f32_16x16x32_bf16(af[m], bfr[n], acc[m][n], 0, 0, 0);
    __builtin_amdgcn_sched_barrier(0);
    __builtin_amdgcn_s_barrier();        // all reads of cur done -> safe to restage next iter
    cur ^= 1;
  }
  __builtin_amdgcn_sched_barrier(0);
  asm volatile("s_waitcnt vmcnt(0)" ::: "memory");
  __builtin_amdgcn_s_barrier();
  __builtin_amdgcn_sched_barrier(0);
  const int cb = cur * 4096;
  short8 af[4], bfr[4];
#pragma unroll
  for (int m = 0; m < 4; ++m) af[m] = *(const short8*)(As + cb + roffA[m]);
#pragma unroll
  for (int n = 0; n < 4; ++n) bfr[n] = *(const short8*)(Bs + cb + roffB[n]);
#pragma unroll
  for (int m = 0; m < 4; ++m)
#pragma unroll
    for (int n = 0; n < 4; ++n)
      acc[m][n] = __builtin_amdgcn_mfma_f32_16x16x32_bf16(af[m], bfr[n], acc[m][n], 0, 0, 0);
}

// ===== mega QKV GEMM: per z-context computes everything derived from one x =====
// N=2560 col split: [0,768) qT self; [768,1280) kvS (interleaved);
// [1280,2048) qT cross; [2048,2560) kvX (interleaved).
__global__ __launch_bounds__(256)
void gemm_qkv_k(const unsigned short* __restrict__ A0, const unsigned short* __restrict__ A1,
                const unsigned short* __restrict__ BT0, const unsigned short* __restrict__ BT1,
                unsigned short* __restrict__ qT0, unsigned short* __restrict__ qT1,
                unsigned short* __restrict__ kvS0, unsigned short* __restrict__ kvS1,
                unsigned short* __restrict__ kvX0, unsigned short* __restrict__ kvX1,
                int M)
{
  const int z = blockIdx.z;
  const unsigned short* A  = z ? A1  : A0;
  const unsigned short* BT = z ? BT1 : BT0;
  unsigned short* qT  = z ? qT1  : qT0;
  unsigned short* kvS = z ? kvS1 : kvS0;
  unsigned short* kvX = z ? kvX1 : kvX0;
  const int K = 256, lda = 256;

  __shared__ __align__(16) unsigned short As[2 * 4096];
  __shared__ __align__(16) unsigned short Bs[2 * 4096];
  const int tid = threadIdx.x;
  const int bm = blockIdx.x * 128, bn = blockIdx.y * 128;
  const int lane = tid & 63, w = tid >> 6;
  const int wr = w >> 1, wc = w & 1;
  const int l15 = lane & 15, kg = lane >> 4;
  const int srow0 = w * 16 + (lane >> 2);
  const int srow1 = 64 + srow0;
  const int sslot = lane & 3;
  const int koff0 = (((sslot - (srow0 >> 1)) & 3)) * 8;
  const int koff1 = (((sslot - (srow1 >> 1)) & 3)) * 8;
  const unsigned short* gA0 = A + (size_t)(bm + srow0) * lda + koff0;
  const unsigned short* gA1 = A + (size_t)(bm + srow1) * lda + koff1;
  const unsigned short* gB0 = BT + (size_t)(bn + srow0) * K + koff0;
  const unsigned short* gB1 = BT + (size_t)(bn + srow1) * K + koff1;
  const int lo0 = w * 512;
  const int lo1 = 2048 + w * 512;

  int roffA[4], roffB[4];
#pragma unroll
  for (int m = 0; m < 4; ++m) {
    int row = wr * 64 + m * 16 + l15;
    roffA[m] = row * 32 + ((kg + (row >> 1)) & 3) * 8;
  }
#pragma unroll
  for (int n = 0; n < 4; ++n) {
    int col = wc * 64 + n * 16 + l15;
    roffB[n] = col * 32 + ((kg + (col >> 1)) & 3) * 8;
  }

  f32x4 acc[4][4] = {};
  kloop_db(gA0, gA1, gB0, gB1, As, Bs, lo0, lo1, roffA, roffB, acc, K);

#pragma unroll
  for (int m = 0; m < 4; ++m) {
#pragma unroll
    for (int n = 0; n < 4; ++n) {
      int col = bn + wc * 64 + n * 16 + l15;
      f32x4 v = acc[m][n];
#pragma unroll
      for (int r2 = 0; r2 < 4; ++r2) {
        int row = bm + wr * 64 + m * 16 + kg * 4 + r2;
        unsigned short bv = f2bf(v[r2]);
        if (col < 768) {
          qT[(size_t)row * 1536 + col] = bv;
        } else if (col < 1280) {
          kvS[(size_t)row * 512 + ileave512(col - 768)] = bv;
        } else if (col < 2048) {
          qT[(size_t)row * 1536 + 768 + (col - 1280)] = bv;
        } else {
          kvX[(size_t)row * 512 + ileave512(col - 2048)] = bv;
        }
      }
    }
  }
}

// ===== generic 2-context bf16 MFMA GEMM (blockIdx.z = L/R) =====
// col split: [0,Sf)->f32 Cf, [Sf,S2)->bf16 Cb1, [S2,N)->bf16 Cb2 (plain layouts).
template<bool BIAS, bool GELU>
__global__ __launch_bounds__(256)
void gemm_mfma2_k(const unsigned short* __restrict__ A0, const unsigned short* __restrict__ A1,
                  int lda,
                  const unsigned short* __restrict__ BT0, const unsigned short* __restrict__ BT1,
                  const float* __restrict__ bias0, const float* __restrict__ bias1,
                  float* __restrict__ Cf0, float* __restrict__ Cf1, int Sf, int ldf,
                  unsigned short* __restrict__ Cb10, unsigned short* __restrict__ Cb11,
                  int S2, int ldb1,
                  unsigned short* __restrict__ Cb20, unsigned short* __restrict__ Cb21, int ldb2,
                  int M, int N, int K)
{
  const int z = blockIdx.z;
  const unsigned short* A  = z ? A1  : A0;
  const unsigned short* BT = z ? BT1 : BT0;
  const float* bias        = z ? bias1 : bias0;
  float* Cf                = z ? Cf1 : Cf0;
  unsigned short* Cb1      = z ? Cb11 : Cb10;
  unsigned short* Cb2      = z ? Cb21 : Cb20;

  __shared__ __align__(16) unsigned short As[2 * 4096];
  __shared__ __align__(16) unsigned short Bs[2 * 4096];
  const int tid = threadIdx.x;
  const int bm = blockIdx.x * 128, bn = blockIdx.y * 128;
  const int lane = tid & 63, w = tid >> 6;
  const int wr = w >> 1, wc = w & 1;
  const int l15 = lane & 15, kg = lane >> 4;
  const int srow0 = w * 16 + (lane >> 2);
  const int srow1 = 64 + srow0;
  const int sslot = lane & 3;
  const int koff0 = (((sslot - (srow0 >> 1)) & 3)) * 8;
  const int koff1 = (((sslot - (srow1 >> 1)) & 3)) * 8;
  const unsigned short* gA0 = A + (size_t)(bm + srow0) * lda + koff0;
  const unsigned short* gA1 = A + (size_t)(bm + srow1) * lda + koff1;
  const unsigned short* gB0 = BT + (size_t)(bn + srow0) * K + koff0;
  const unsigned short* gB1 = BT + (size_t)(bn + srow1) * K + koff1;
  const int lo0 = w * 512;
  const int lo1 = 2048 + w * 512;

  int roffA[4], roffB[4];
#pragma unroll
  for (int m = 0; m < 4; ++m) {
    int row = wr * 64 + m * 16 + l15;
    roffA[m] = row * 32 + ((kg + (row >> 1)) & 3) * 8;
  }
#pragma unroll
  for (int n = 0; n < 4; ++n) {
    int col = wc * 64 + n * 16 + l15;
    roffB[n] = col * 32 + ((kg + (col >> 1)) & 3) * 8;
  }

  f32x4 acc[4][4] = {};
  kloop_db(gA0, gA1, gB0, gB1, As, Bs, lo0, lo1, roffA, roffB, acc, K);

#pragma unroll
  for (int m = 0; m < 4; ++m) {
#pragma unroll
    for (int n = 0; n < 4; ++n) {
      int col = bn + wc * 64 + n * 16 + l15;
      float bv = BIAS ? bias[col] : 0.f;
      f32x4 v = acc[m][n];
#pragma unroll
      for (int r2 = 0; r2 < 4; ++r2) {
        int row = bm + wr * 64 + m * 16 + kg * 4 + r2;
        float val = v[r2] + bv;
        if (GELU) val = gelu_f(val);
        if (col < Sf) {
          Cf[(size_t)row * ldf + col] = val;
        } else if (col < S2) {
          Cb1[(size_t)row * ldb1 + (col - Sf)] = f2bf(val);
        } else {
          Cb2[(size_t)row * ldb2 + (col - S2)] = f2bf(val);
        }
      }
    }
  }
}

// ===== f32 GEMM, 2-context (tiny N=7 head2) =====
template<bool BIAS>
__global__ __launch_bounds__(256)
void gemm_k2(const float* __restrict__ A0, const float* __restrict__ A1,
             const float* __restrict__ B, const float* __restrict__ bias,
             float* __restrict__ C0, float* __restrict__ C1,
             int M, int N, int K)
{
  const float* A = blockIdx.z ? A1 : A0;
  float* C = blockIdx.z ? C1 : C0;
  __shared__ float As[16][132];
  __shared__ float Bs[16][132];
  const int tid = threadIdx.x;
  const int tx = tid & 15, ty = tid >> 4;
  const int bm = blockIdx.x * 128;
  float acc[8][8];
#pragma unroll
  for (int i = 0; i < 8; ++i)
#pragma unroll
    for (int j = 0; j < 8; ++j) acc[i][j] = 0.f;
  const int ar = tid >> 1;
  const int ac = (tid & 1) * 8;
  const int br = tid >> 4;
  const int bc = (tid & 15) * 8;
  for (int k0 = 0; k0 < K; k0 += 16) {
    {
      float av[8] = {0,0,0,0,0,0,0,0};
      if (bm + ar < M) {
        const float* app = A + (size_t)(bm + ar) * K + (k0 + ac);
        float4 a0 = *(const float4*)app;
        float4 a1 = *(const float4*)(app + 4);
        av[0]=a0.x; av[1]=a0.y; av[2]=a0.z; av[3]=a0.w;
        av[4]=a1.x; av[5]=a1.y; av[6]=a1.z; av[7]=a1.w;
      }
#pragma unroll
      for (int i = 0; i < 8; ++i) As[ac + i][ar] = av[i];
    }
    {
      float bv[8] = {0,0,0,0,0,0,0,0};
      const float* bpp = B + (size_t)(k0 + br) * N + bc;
#pragma unroll
      for (int i = 0; i < 8; ++i) { if (bc + i < N) bv[i] = bpp[i]; }
#pragma unroll
      for (int i = 0; i < 8; ++i) Bs[br][bc + i] = bv[i];
    }
    __syncthreads();
#pragma unroll
    for (int kk = 0; kk < 16; ++kk) {
      float a[8], b[8];
      float4 t0 = *(const float4*)&As[kk][ty * 8];
      float4 t1 = *(const float4*)&As[kk][ty * 8 + 4];
      float4 u0 = *(const float4*)&Bs[kk][tx * 8];
      float4 u1 = *(const float4*)&Bs[kk][tx * 8 + 4];
      a[0]=t0.x;a[1]=t0.y;a[2]=t0.z;a[3]=t0.w;a[4]=t1.x;a[5]=t1.y;a[6]=t1.z;a[7]=t1.w;
      b[0]=u0.x;b[1]=u0.y;b[2]=u0.z;b[3]=u0.w;b[4]=u1.x;b[5]=u1.y;b[6]=u1.z;b[7]=u1.w;
#pragma unroll
      for (int i = 0; i < 8; ++i)
#pragma unroll
        for (int j = 0; j < 8; ++j)
          acc[i][j] = fmaf(a[i], b[j], acc[i][j]);
    }
    __syncthreads();
  }
#pragma unroll
  for (int i = 0; i < 8; ++i) {
    int row = bm + ty * 8 + i;
    if (row >= M) continue;
    int colg = tx * 8;
    float* cp = C + (size_t)row * N + colg;
#pragma unroll
    for (int j = 0; j < 8; ++j) {
      int cc = colg + j;
      if (cc < N) {
        float val = acc[i][j];
        if (BIAS) val += bias[cc];
        cp[j] = val;
      }
    }
  }
}

// ===== generic transpose+convert (FFN / head weights) =====
__global__ void tc_k(const float* __restrict__ in, unsigned short* __restrict__ out,
                     int K, int N, int inStride, int outStride, int rowOff, int totK, int kOff)
{
  const int mat = blockIdx.y;
  const int idx = blockIdx.x * 256 + threadIdx.x;
  if (idx >= N * K) return;
  const int n = idx / K, k = idx - n * K;
  out[(size_t)mat * outStride + (size_t)(rowOff + n) * totK + kOff + k] =
      f2bf(in[(size_t)mat * inStride + (size_t)k * N + n]);
}

// ===== mega-QKV weight pack: 6 parts x 4 slots (l,side) =====
__global__ void tc_all_k(const float* __restrict__ Wq, const float* __restrict__ Wk,
                         const float* __restrict__ Wv, unsigned short* __restrict__ BTall)
{
  const int part = blockIdx.z;
  const int slot = blockIdx.y;
  const int l = slot >> 1, zz = slot & 1;
  const int self = l * 4 + zz;
  const int crossq = l * 4 + (zz ? 2 : 3);
  const int crosskv = l * 4 + (zz ? 3 : 2);
  const float* in; int mat, rowOff;
  switch (part) {
    case 0: in = Wq; mat = self;    rowOff = 0;    break;
    case 1: in = Wk; mat = self;    rowOff = 768;  break;
    case 2: in = Wv; mat = self;    rowOff = 1024; break;
    case 3: in = Wq; mat = crossq;  rowOff = 1280; break;
    case 4: in = Wk; mat = crosskv; rowOff = 2048; break;
    default:in = Wv; mat = crosskv; rowOff = 2304; break;
  }
  const int idx = blockIdx.x * 256 + threadIdx.x;
  const int n = idx >> 8, k = idx & 255;
  BTall[(size_t)slot * 655360 + (size_t)(rowOff + n) * 256 + k] =
      f2bf(in[(size_t)mat * 65536 + (size_t)k * 256 + n]);
}

// ===== fused T-weights inside BTall (self rows 256..767; cross rows 1536..2047) =====
__global__ __launch_bounds__(256)
void wqe2_k(unsigned short* __restrict__ BTall, const float* __restrict__ We)
{
  const int which = blockIdx.z;        // 0 self, 1 cross
  const int slot = blockIdx.y;
  const int l = slot >> 1, zz = slot & 1;
  const int mat = which ? (l * 4 + (zz ? 2 : 3)) : (l * 4 + zz);
  const int baseQ = which ? 1280 : 0;
  const int baseT = which ? 1536 : 256;
  const int oc = blockIdx.x;           // 0..511 = head*64 + c
  const int g = oc >> 6, cc = oc & 63;
  const int kin = threadIdx.x;         // 0..255
  const float* wrow = We + (size_t)mat * 16384 + (size_t)cc * 256 + g * 32;
  const unsigned short* bq = BTall + (size_t)slot * 655360 + (size_t)(baseQ + g * 32) * 256 + kin;
  float acc = 0.f;
#pragma unroll 8
  for (int d = 0; d < 32; ++d)
    acc += bf2f(bq[(size_t)d * 256]) * wrow[d];
  BTall[(size_t)slot * 655360 + (size_t)(baseT + oc) * 256 + kin] = f2bf(acc);
}

// ===== fused Wo pack: BTwoF[sl][n][base + k] = Wo[mat][k][n] =====
__global__ void wo_tc_k(const float* __restrict__ Wo, unsigned short* __restrict__ BTwoF)
{
  const int mat = blockIdx.y;          // 0..7 = l*4+i
  const int idx = blockIdx.x * 256 + threadIdx.x;
  const int n = idx >> 8, k = idx & 255;
  const int l = mat >> 2, i = mat & 3;
  const int side = (i == 1 || i == 2) ? 1 : 0;
  const int base = (i >= 2) ? 768 : 0;
  BTwoF[(size_t)(l * 2 + side) * 393216 + (size_t)n * 1536 + base + k] =
      f2bf(Wo[(size_t)mat * 65536 + (size_t)k * 256 + n]);
}

// ===== Wc fold: BTwoF[sl][n][base + 256 + h*64+c] = sum_d We[c,h*32+d]*Wo[h*32+d,n] =====
__global__ __launch_bounds__(256)
void wc_k(const float* __restrict__ We, const float* __restrict__ Wo,
          unsigned short* __restrict__ BTwoF)
{
  const int mat = blockIdx.y;          // 0..7 = l*4+i
  const int j = blockIdx.x;            // 0..511 = h*64+c
  const int h = j >> 6, c = j & 63;
  const int n = threadIdx.x;           // 0..255
  const float* wep = We + (size_t)mat * 16384 + (size_t)c * 256 + h * 32;
  const float* wop = Wo + (size_t)mat * 65536 + (size_t)(h * 32) * 256 + n;
  float acc = 0.f;
#pragma unroll 8
  for (int d = 0; d < 32; ++d)
    acc += wep[d] * wop[(size_t)d * 256];
  const int l = mat >> 2, i = mat & 3;
  const int side = (i == 1 || i == 2) ? 1 : 0;
  const int base = (i >= 2) ? 768 : 0;
  BTwoF[(size_t)(l * 2 + side) * 393216 + (size_t)n * 1536 + base + 256 + j] = f2bf(acc);
}

// ===== per-dst online-softmax edge aggregation, 4 contexts via blockIdx.y =====
// 2-edge loop; ea loads nontemporal (zero-reuse stream).
__global__ __launch_bounds__(256)
void edge4_k(const int* __restrict__ o0, const int* __restrict__ o1,
             const int* __restrict__ o2, const int* __restrict__ o3,
             const int2* __restrict__ p0, const int2* __restrict__ p1,
             const int2* __restrict__ p2, const int2* __restrict__ p3,
             const float* __restrict__ e0, const float* __restrict__ e1,
             const float* __restrict__ e2, const float* __restrict__ e3,
             unsigned short* q0, unsigned short* q1,
             unsigned short* q2, unsigned short* q3,
             const unsigned short* __restrict__ k0, const unsigned short* __restrict__ k1,
             const unsigned short* __restrict__ k2, const unsigned short* __restrict__ k3,
             int Nn)
{
  const int y = blockIdx.y;
  const int* offs = (y == 0) ? o0 : (y == 1) ? o1 : (y == 2) ? o2 : o3;
  const int2* pairs = (y == 0) ? p0 : (y == 1) ? p1 : (y == 2) ? p2 : p3;
  const float* ea = (y == 0) ? e0 : (y == 1) ? e1 : (y == 2) ? e2 : e3;
  unsigned short* qTmsg = (y == 0) ? q0 : (y == 1) ? q1 : (y == 2) ? q2 : q3;
  const unsigned short* kv = (y == 0) ? k0 : (y == 1) ? k1 : (y == 2) ? k2 : k3;
  const int wv = (blockIdx.x * blockDim.x + threadIdx.x) >> 6;
  if (wv >= Nn) return;
  const int lane = threadIdx.x & 63;
  const int g = lane >> 3, p = lane & 7;
  const float scale = 0.17677669529663687f;
  const ushort4 qu = *(const ushort4*)(qTmsg + (size_t)wv * 1536 + lane * 4);
  const float qx = bf2f(qu.x), qy = bf2f(qu.y), qz = bf2f(qu.z), qw = bf2f(qu.w);
  const unsigned short* Tp = qTmsg + (size_t)wv * 1536 + 256 + g * 64 + p * 8;
  const ushort4 tu0 = *(const ushort4*)Tp;
  const ushort4 tu1 = *(const ushort4*)(Tp + 4);
  const float Ta0 = bf2f(tu0.x), Ta1 = bf2f(tu0.y), Ta2 = bf2f(tu0.z), Ta3 = bf2f(tu0.w);
  const float Tc0 = bf2f(tu1.x), Tc1 = bf2f(tu1.y), Tc2 = bf2f(tu1.z), Tc3 = bf2f(tu1.w);
  float m = -INFINITY, den = 0.f;
  float ax = 0.f, ay = 0.f, az = 0.f, aw = 0.f;
  float G[8] = {0,0,0,0,0,0,0,0};
  const int e0i = __builtin_amdgcn_readfirstlane(offs[wv]);
  const int e1i = __builtin_amdgcn_readfirstlane(offs[wv + 1]);
  for (int j = e0i; j < e1i; j += 2) {
    const bool hasB = (j + 1) < e1i;
    const int2 prA = pairs[j];
    const int2 prB = hasB ? pairs[j + 1] : prA;
    const f32x4* epA = (const f32x4*)(ea + (size_t)prA.x * 64 + p * 8);
    const f32x4* epB = (const f32x4*)(ea + (size_t)prB.x * 64 + p * 8);
    const f32x4 a0 = __builtin_nontemporal_load(epA);
    const f32x4 a1 = __builtin_nontemporal_load(epA + 1);
    const f32x4 b0 = __builtin_nontemporal_load(epB);
    const f32x4 b1 = __builtin_nontemporal_load(epB + 1);
    const short8 kvA = *(const short8*)(kv + (size_t)prA.y * 512 + lane * 8);
    const short8 kvB = *(const short8*)(kv + (size_t)prB.y * 512 + lane * 8);
    float pA = qx * bf2f((unsigned short)kvA[0]) + qy * bf2f((unsigned short)kvA[1])
             + qz * bf2f((unsigned short)kvA[2]) + qw * bf2f((unsigned short)kvA[3]);
    pA += a0[0]*Ta0 + a0[1]*Ta1 + a0[2]*Ta2 + a0[3]*Ta3;
    pA += a1[0]*Tc0 + a1[1]*Tc1 + a1[2]*Tc2 + a1[3]*Tc3;
    float pB = qx * bf2f((unsigned short)kvB[0]) + qy * bf2f((unsigned short)kvB[1])
             + qz * bf2f((unsigned short)kvB[2]) + qw * bf2f((unsigned short)kvB[3]);
    pB += b0[0]*Ta0 + b0[1]*Ta1 + b0[2]*Ta2 + b0[3]*Ta3;
    pB += b1[0]*Tc0 + b1[1]*Tc1 + b1[2]*Tc2 + b1[3]*Tc3;
    pA += __shfl_xor(pA, 1, 64); pA += __shfl_xor(pA, 2, 64); pA += __shfl_xor(pA, 4, 64);
    pB += __shfl_xor(pB, 1, 64); pB += __shfl_xor(pB, 2, 64); pB += __shfl_xor(pB, 4, 64);
    const float sA = pA * scale;
    const float sB = hasB ? pB * scale : -INFINITY;
    const float mn = fmaxf(m, fmaxf(sA, sB));
    const float corr = __expf(m - mn);   // exp(-inf)=0 on first iteration
    const float wA = __expf(sA - mn);
    const float wB = __expf(sB - mn);
    m = mn;
    den = den * corr + wA + wB;
    ax = ax * corr + wA * bf2f((unsigned short)kvA[4]) + wB * bf2f((unsigned short)kvB[4]);
    ay = ay * corr + wA * bf2f((unsigned short)kvA[5]) + wB * bf2f((unsigned short)kvB[5]);
    az = az * corr + wA * bf2f((unsigned short)kvA[6]) + wB * bf2f((unsigned short)kvB[6]);
    aw = aw * corr + wA * bf2f((unsigned short)kvA[7]) + wB * bf2f((unsigned short)kvB[7]);
    G[0] = G[0] * corr + wA * a0[0] + wB * b0[0];
    G[1] = G[1] * corr + wA * a0[1] + wB * b0[1];
    G[2] = G[2] * corr + wA * a0[2] + wB * b0[2];
    G[3] = G[3] * corr + wA * a0[3] + wB * b0[3];
    G[4] = G[4] * corr + wA * a1[0] + wB * b1[0];
    G[5] = G[5] * corr + wA * a1[1] + wB * b1[1];
    G[6] = G[6] * corr + wA * a1[2] + wB * b1[2];
    G[7] = G[7] * corr + wA * a1[3] + wB * b1[3];
  }
  const float inv = 1.f / (den + 1e-9f);
  ushort4 o;
  o.x = f2bf(ax * inv); o.y = f2bf(ay * inv);
  o.z = f2bf(az * inv); o.w = f2bf(aw * inv);
  *(ushort4*)(qTmsg + (size_t)wv * 1536 + lane * 4) = o;
  short8 gn;
#pragma unroll
  for (int i = 0; i < 8; ++i) gn[i] = (short)f2bf(G[i] * inv);
  *(short8*)(qTmsg + (size_t)wv * 1536 + 256 + g * 64 + p * 8) = gn;
}

// ===== residual add + LayerNorm on bf16 carry (L/R via blockIdx.y); add is bf16 =====
__global__ __launch_bounds__(256)
void add_ln2_k(unsigned short* __restrict__ xbL, const unsigned short* __restrict__ addL,
               unsigned short* __restrict__ xbR, const unsigned short* __restrict__ addR, int Nn)
{
  unsigned short* xb = blockIdx.y ? xbR : xbL;
  const unsigned short* add = blockIdx.y ? addR : addL;
  const int wv = (blockIdx.x * blockDim.x + threadIdx.x) >> 6;
  if (wv >= Nn) return;
  const int lane = threadIdx.x & 63;
  ushort4 xu = *(const ushort4*)(xb + (size_t)wv * 256 + lane * 4);
  ushort4 au = *(const ushort4*)(add + (size_t)wv * 256 + lane * 4);
  float4 y;
  y.x = bf2f(xu.x) + bf2f(au.x); y.y = bf2f(xu.y) + bf2f(au.y);
  y.z = bf2f(xu.z) + bf2f(au.z); y.w = bf2f(xu.w) + bf2f(au.w);
  float s = y.x + y.y + y.z + y.w;
#pragma unroll
  for (int msk = 1; msk < 64; msk <<= 1) s += __shfl_xor(s, msk, 64);
  const float mean = s * (1.f / 256.f);
  float4 d;
  d.x = y.x - mean; d.y = y.y - mean; d.z = y.z - mean; d.w = y.w - mean;
  float sq = d.x*d.x + d.y*d.y + d.z*d.z + d.w*d.w;
#pragma unroll
  for (int msk = 1; msk < 64; msk <<= 1) sq += __shfl_xor(sq, msk, 64);
  const float r = rsqrtf(sq * (1.f / 256.f) + 1e-5f);
  ushort4 ob;
  ob.x = f2bf(d.x * r); ob.y = f2bf(d.y * r);
  ob.z = f2bf(d.z * r); ob.w = f2bf(d.w * r);
  *(ushort4*)(xb + (size_t)wv * 256 + lane * 4) = ob;
}

// ===== init: f32 input -> bf16 carry (L/R via blockIdx.y) =====
__global__ void cvt_x2_k(const float* __restrict__ aL, unsigned short* __restrict__ xbL,
                         const float* __restrict__ aR, unsigned short* __restrict__ xbR, int n4)
{
  const float* a = blockIdx.y ? aR : aL;
  unsigned short* xb = blockIdx.y ? xbR : xbL;
  int i = blockIdx.x * 256 + threadIdx.x;
  if (i >= n4) return;
  float4 v = ((const float4*)a)[i];
  ushort4 b;
  b.x = f2bf(v.x); b.y = f2bf(v.y); b.z = f2bf(v.z); b.w = f2bf(v.w);
  ((ushort4*)xb)[i] = b;
}

// ===== CSR kernels =====
__global__ void zero4_k(int* p, int n) {
  int i = blockIdx.x * 256 + threadIdx.x;
  if (i < n) p[i] = 0;
}
__global__ void hist4_k(const int* d0, const int* d1, const int* d2, const int* d3,
                        int E0, int E1, int E2, int E3, int* cnt, int Nn) {
  const int s = blockIdx.y;
  const int* d = (s == 0) ? d0 : (s == 1) ? d1 : (s == 2) ? d2 : d3;
  const int E = (s == 0) ? E0 : (s == 1) ? E1 : (s == 2) ? E2 : E3;
  int e = blockIdx.x * 256 + threadIdx.x;
  if (e < E) atomicAdd(&cnt[s * Nn + d[e]], 1);
}
__global__ __launch_bounds__(256)
void scan4_k(const int* __restrict__ cnt, int* __restrict__ offs, int* __restrict__ cursor, int Nn)
{
  __shared__ int sums[256];
  const int s = blockIdx.x;
  const int t = threadIdx.x;
  const int* c = cnt + (size_t)s * Nn;
  int* o = offs + (size_t)s * (Nn + 1);
  int* cur = cursor + (size_t)s * Nn;
  const int chunk = (Nn + 255) / 256;
  const int base = t * chunk;
  int sl = 0;
  for (int i = 0; i < chunk; ++i) {
    int idx = base + i;
    if (idx < Nn) sl += c[idx];
  }
  sums[t] = sl;
  __syncthreads();
  for (int off = 1; off < 256; off <<= 1) {
    int val = (t >= off) ? sums[t - off] : 0;
    __syncthreads();
    sums[t] += val;
    __syncthreads();
  }
  int run = (t == 0) ? 0 : sums[t - 1];
  for (int i = 0; i < chunk; ++i) {
    int idx = base + i;
    if (idx < Nn) { o[idx] = run; cur[idx] = run; run += c[idx]; }
  }
  if (t == 255) o[Nn] = run;
}
__global__ void scatter4_k(const int* e0p, const int* e1p, const int* e2p, const int* e3p,
                           int E0, int E1, int E2, int E3, int* cursor,
                           int2* p0, int2* p1, int2* p2, int2* p3, int Nn) {
  const int s = blockIdx.y;
  const int* ei = (s == 0) ? e0p : (s == 1) ? e1p : (s == 2) ? e2p : e3p;
  int2* po = (s == 0) ? p0 : (s == 1) ? p1 : (s == 2) ? p2 : p3;
  const int E = (s == 0) ? E0 : (s == 1) ? E1 : (s == 2) ? E2 : E3;
  int e = blockIdx.x * 256 + threadIdx.x;
  if (e < E) {
    int pos = atomicAdd(&cursor[s * Nn + ei[E + e]], 1);
    po[pos] = make_int2(e, ei[e]);
  }
}

// ===== host orchestration =====
extern "C" void kernel_launch(void* const* d_in, const int* in_sizes, int n_in,
                              void* d_out, int out_size, void* d_ws, size_t ws_size,
                              hipStream_t stream)
{
  (void)n_in; (void)ws_size;
  const float* afl = (const float*)d_in[0];
  const float* afr = (const float*)d_in[1];
  const float* eaA[4] = {(const float*)d_in[2], (const float*)d_in[3],
                         (const float*)d_in[4], (const float*)d_in[5]};
  const int* eiA[4] = {(const int*)d_in[6], (const int*)d_in[7],
                       (const int*)d_in[8], (const int*)d_in[9]};
  const float* Wq  = (const float*)d_in[10];
  const float* Wk  = (const float*)d_in[11];
  const float* Wv  = (const float*)d_in[12];
  const float* We  = (const float*)d_in[13];
  const float* Wo  = (const float*)d_in[14];
  const float* fw1 = (const float*)d_in[15];
  const float* fb1 = (const float*)d_in[16];
  const float* fw2 = (const float*)d_in[17];
  const float* fb2 = (const float*)d_in[18];
  const float* hw1 = (const float*)d_in[19];
  const float* hb1 = (const float*)d_in[20];
  const float* hw2 = (const float*)d_in[21];
  const float* hb2 = (const float*)d_in[22];

  const int Nn = in_sizes[0] / 256;
  const int E[4] = {in_sizes[2] / 64, in_sizes[3] / 64, in_sizes[4] / 64, in_sizes[5] / 64};
  const int Mh = out_size / 14;
  const int astart = Nn - Mh;
  float* out = (float*)d_out;

  // workspace ~244 MB: xb 19 + agg 19 + qTmsg 113 + kv(4) 76 + weights 11 + csr/pairs 7
  char* wsp = (char*)d_ws;
  auto alloc = [&](size_t bytes) -> void* {
    void* pp = (void*)wsp;
    wsp += (bytes + 255) & ~(size_t)255;
    return pp;
  };
  unsigned short* xlb = (unsigned short*)alloc((size_t)Nn * 256 * 2);
  unsigned short* xrb = (unsigned short*)alloc((size_t)Nn * 256 * 2);
  unsigned short* aggLb = (unsigned short*)alloc((size_t)Nn * 256 * 2);
  unsigned short* aggRb = (unsigned short*)alloc((size_t)Nn * 256 * 2);
  unsigned short* qTmsgA = (unsigned short*)alloc((size_t)Nn * 1536 * 2);
  unsigned short* qTmsgB = (unsigned short*)alloc((size_t)Nn * 1536 * 2);
  unsigned short* kvSA = (unsigned short*)alloc((size_t)Nn * 512 * 2);  // ll kv; FFN hidden; head f32 scratch
  unsigned short* kvSB = (unsigned short*)alloc((size_t)Nn * 512 * 2);
  unsigned short* kvXL = (unsigned short*)alloc((size_t)Nn * 512 * 2);  // lr kv (from xl)
  unsigned short* kvXR = (unsigned short*)alloc((size_t)Nn * 512 * 2);  // rl kv (from xr)
  unsigned short* BTall = (unsigned short*)alloc((size_t)4 * 655360 * 2);
  unsigned short* BTwoF = (unsigned short*)alloc((size_t)4 * 256 * 1536 * 2);
  unsigned short* BTf1  = (unsigned short*)alloc((size_t)4 * 512 * 256 * 2);
  unsigned short* BTf2  = (unsigned short*)alloc((size_t)4 * 256 * 512 * 2);
  unsigned short* BTh1  = (unsigned short*)alloc((size_t)256 * 256 * 2);
  int* offs4 = (int*)alloc((size_t)4 * (Nn + 1) * 4);
  int* cnt4  = (int*)alloc((size_t)4 * Nn * 4);
  int* cur4  = (int*)alloc((size_t)4 * Nn * 4);
  int2* pairs[4];
  for (int s = 0; s < 4; ++s) pairs[s] = (int2*)alloc((size_t)E[s] * 8);

  const dim3 B256(256);
  const int wgNodes = (Nn * 64 + 255) / 256;
  int maxE = E[0];
  for (int s = 1; s < 4; ++s) if (E[s] > maxE) maxE = E[s];

  // ---- init xb, CSR pair lists ----
  cvt_x2_k<<<dim3((Nn * 64 + 255) / 256, 2), B256, 0, stream>>>(afl, xlb, afr, xrb, Nn * 64);
  zero4_k<<<dim3((4 * Nn + 255) / 256), B256, 0, stream>>>(cnt4, 4 * Nn);
  {
    dim3 gh((maxE + 255) / 256, 4);
    hist4_k<<<gh, B256, 0, stream>>>(eiA[0] + E[0], eiA[1] + E[1], eiA[2] + E[2], eiA[3] + E[3],
                                     E[0], E[1], E[2], E[3], cnt4, Nn);
    scan4_k<<<dim3(4), B256, 0, stream>>>(cnt4, offs4, cur4, Nn);
    scatter4_k<<<gh, B256, 0, stream>>>(eiA[0], eiA[1], eiA[2], eiA[3],
                                        E[0], E[1], E[2], E[3], cur4,
                                        pairs[0], pairs[1], pairs[2], pairs[3], Nn);
  }
  // ---- weight conversion ----
  {
    tc_all_k<<<dim3(256, 4, 6), B256, 0, stream>>>(Wq, Wk, Wv, BTall);
    wqe2_k<<<dim3(512, 4, 2), B256, 0, stream>>>(BTall, We);
    wo_tc_k<<<dim3(256, 8), B256, 0, stream>>>(Wo, BTwoF);
    wc_k<<<dim3(512, 8), B256, 0, stream>>>(We, Wo, BTwoF);
    tc_k<<<dim3((131072 + 255) / 256, 4), B256, 0, stream>>>(fw1, BTf1, 256, 512, 131072, 131072, 0, 256, 0);
    tc_k<<<dim3((131072 + 255) / 256, 4), B256, 0, stream>>>(fw2, BTf2, 512, 256, 131072, 131072, 0, 512, 0);
    tc_k<<<dim3((65536 + 255) / 256, 1), B256, 0, stream>>>(hw1, BTh1, 256, 256, 0, 0, 0, 256, 0);
  }

  auto mfma2 = [&](const unsigned short* A0, const unsigned short* A1, int lda,
                   const unsigned short* BT0, const unsigned short* BT1,
                   const float* bias0, const float* bias1,
                   float* Cf0, float* Cf1, int Sf, int ldf,
                   unsigned short* Cb10, unsigned short* Cb11, int S2, int ldb1,
                   unsigned short* Cb20, unsigned short* Cb21, int ldb2,
                   int M, int N, int K, bool biasf, bool gelu) {
    dim3 g(M / 128, N / 128, 2);
    if (biasf && gelu)
      gemm_mfma2_k<true, true ><<<g, B256, 0, stream>>>(A0, A1, lda, BT0, BT1, bias0, bias1,
          Cf0, Cf1, Sf, ldf, Cb10, Cb11, S2, ldb1, Cb20, Cb21, ldb2, M, N, K);
    else if (biasf)
      gemm_mfma2_k<true, false><<<g, B256, 0, stream>>>(A0, A1, lda, BT0, BT1, bias0, bias1,
          Cf0, Cf1, Sf, ldf, Cb10, Cb11, S2, ldb1, Cb20, Cb21, ldb2, M, N, K);
    else
      gemm_mfma2_k<false, false><<<g, B256, 0, stream>>>(A0, A1, lda, BT0, BT1, bias0, bias1,
          Cf0, Cf1, Sf, ldf, Cb10, Cb11, S2, ldb1, Cb20, Cb21, ldb2, M, N, K);
  };

  for (int l = 0; l < 2; ++l) {
    // 1) mega QKV: everything derived from xl (z0) and xr (z1)
    gemm_qkv_k<<<dim3(Nn / 128, 20, 2), B256, 0, stream>>>(
        xlb, xrb,
        BTall + (size_t)(l * 2 + 0) * 655360, BTall + (size_t)(l * 2 + 1) * 655360,
        qTmsgA, qTmsgB, kvSA, kvSB, kvXL, kvXR, Nn);
    // 2) all four edge aggregations in one dispatch
    edge4_k<<<dim3(wgNodes, 4), B256, 0, stream>>>(
        offs4, offs4 + (size_t)(Nn + 1), offs4 + (size_t)3 * (Nn + 1), offs4 + (size_t)2 * (Nn + 1),
        pairs[0], pairs[1], pairs[3], pairs[2],
        eaA[0], eaA[1], eaA[3], eaA[2],
        qTmsgA, qTmsgB, qTmsgA + 768, qTmsgB + 768,
        kvSA, kvSB, kvXR, kvXL, Nn);
    // 3) fused Wo: agg = [selfV|selfGn|crossV|crossGn] @ [Wo_s|Wc_s|Wo_c|Wc_c], K=1536
    mfma2(qTmsgA, qTmsgB, 1536, BTwoF + (size_t)(l*2+0)*393216, BTwoF + (size_t)(l*2+1)*393216,
          nullptr, nullptr, nullptr, nullptr, 0, 0, aggLb, aggRb, 256, 256,
          nullptr, nullptr, 0, Nn, 256, 1536, false, false);
    add_ln2_k<<<dim3(wgNodes, 2), B256, 0, stream>>>(xlb, aggLb, xrb, aggRb, Nn);
    // 4) FFN (L/R combined); kvS buffers reused as hidden (plain layout)
    const int fL = l * 2 + 0, fR = l * 2 + 1;
    mfma2(xlb, xrb, 256, BTf1 + (size_t)fL*131072, BTf1 + (size_t)fR*131072,
          fb1 + (size_t)fL*512, fb1 + (size_t)fR*512, nullptr, nullptr, 0, 0,
          kvSA, kvSB, 512, 512, nullptr, nullptr, 0, Nn, 512, 256, true, true);
    mfma2(kvSA, kvSB, 512, BTf2 + (size_t)fL*131072, BTf2 + (size_t)fR*131072,
          fb2 + (size_t)fL*256, fb2 + (size_t)fR*256, nullptr, nullptr, 0, 0,
          aggLb, aggRb, 256, 256, nullptr, nullptr, 0, Nn, 256, 512, true, false);
    add_ln2_k<<<dim3(wgNodes, 2), B256, 0, stream>>>(xlb, aggLb, xrb, aggRb, Nn);
  }
  // heads: gelu(x@hw1+hb1) -> f32 scratch (kvS), then @ hw2 + hb2
  float* h1L = (float*)kvSA;
  float* h1R = (float*)kvSB;
  mfma2(xlb + (size_t)astart * 256, xrb + (size_t)astart * 256, 256, BTh1, BTh1,
        hb1, hb1, h1L, h1R, 256, 256, nullptr, nullptr, 0, 0, nullptr, nullptr, 0,
        Mh, 256, 256, true, true);
  gemm_k2<true><<<dim3(Mh / 128, 1, 2), B256, 0, stream>>>(h1L, h1R, hw2, hb2,
                                                           out, out + (size_t)Mh * 7, Mh, 7, 256);
}